// Round 1
// baseline (1339.335 us; speedup 1.0000x reference)
//
#include <hip/hip_runtime.h>
#include <hip/hip_bf16.h>

#define HEADS 4
#define CH 64
#define HC 256

// ---------------- CSR build ----------------

__global__ void hist_kernel(const int* __restrict__ dst, int E, int ET, int* __restrict__ cnt){
  int e = blockIdx.x * blockDim.x + threadIdx.x;
  if (e >= ET) return;
  int d = (e < E) ? dst[e] : (e - E);   // self-loop edges appended
  atomicAdd(&cnt[d], 1);
}

__global__ void scan_kernel(const int* __restrict__ cnt, int* __restrict__ ptr,
                            int* __restrict__ cur, int N){
  __shared__ int buf[1024];
  __shared__ int carry;
  int tid = threadIdx.x;
  if (tid == 0) carry = 0;
  __syncthreads();
  for (int base = 0; base < N; base += 1024){
    int i = base + tid;
    int v = (i < N) ? cnt[i] : 0;
    buf[tid] = v;
    __syncthreads();
    #pragma unroll
    for (int off = 1; off < 1024; off <<= 1){
      int t = (tid >= off) ? buf[tid - off] : 0;
      __syncthreads();
      buf[tid] += t;
      __syncthreads();
    }
    int inc = buf[tid];      // inclusive scan within chunk
    int exc = inc - v;
    int c = carry;
    if (i < N){ ptr[i] = c + exc; cur[i] = c + exc; }
    int tot = buf[1023];
    __syncthreads();
    if (tid == 0) carry = c + tot;
    __syncthreads();
  }
  if (tid == 0) ptr[N] = carry;
}

__global__ void scatter_kernel(const int* __restrict__ src, const int* __restrict__ dst,
                               int E, int ET, int* __restrict__ cur, int* __restrict__ csr_src){
  int e = blockIdx.x * blockDim.x + threadIdx.x;
  if (e >= ET) return;
  int s, d;
  if (e < E){ s = src[e]; d = dst[e]; } else { s = e - E; d = e - E; }
  int pos = atomicAdd(&cur[d], 1);
  csr_src[pos] = s;
}

// ---------------- fp32 GEMM: C[M,256] = A[M,K] @ B[K,256] ----------------
// BM=128, BN=64, BK=32, 256 threads, 8x4 micro-tile.

__launch_bounds__(256)
__global__ void gemm_kernel(const float* __restrict__ A, const float* __restrict__ B,
                            float* __restrict__ Cm, int M, int K){
  __shared__ float As[32][132];   // k-major, padded (132*4 % 16 == 0 keeps b128 aligned)
  __shared__ float Bs[32][64];
  int tid = threadIdx.x;
  int tx = tid & 15, ty = tid >> 4;
  int m0 = blockIdx.x * 128, n0 = blockIdx.y * 64;
  float acc[8][4];
  #pragma unroll
  for (int i = 0; i < 8; i++)
    #pragma unroll
    for (int j = 0; j < 4; j++) acc[i][j] = 0.f;

  for (int k0 = 0; k0 < K; k0 += 32){
    #pragma unroll
    for (int q = 0; q < 4; q++){            // A tile: 128x32 = 1024 float4
      int f4 = q * 256 + tid;
      int ar = f4 >> 3, ac4 = f4 & 7;
      int gm = m0 + ar;
      float4 v = make_float4(0.f, 0.f, 0.f, 0.f);
      if (gm < M) v = *(const float4*)&A[(size_t)gm * K + k0 + ac4 * 4];
      As[ac4*4+0][ar] = v.x; As[ac4*4+1][ar] = v.y;
      As[ac4*4+2][ar] = v.z; As[ac4*4+3][ar] = v.w;
    }
    #pragma unroll
    for (int q = 0; q < 2; q++){            // B tile: 32x64 = 512 float4
      int f4 = q * 256 + tid;
      int br = f4 >> 4, bc4 = f4 & 15;
      *(float4*)&Bs[br][bc4*4] = *(const float4*)&B[(size_t)(k0 + br) * HC + n0 + bc4 * 4];
    }
    __syncthreads();
    #pragma unroll
    for (int k = 0; k < 32; k++){
      float4 b  = *(float4*)&Bs[k][tx * 4];
      float4 a0 = *(float4*)&As[k][ty * 8];
      float4 a1 = *(float4*)&As[k][ty * 8 + 4];
      float av[8] = {a0.x, a0.y, a0.z, a0.w, a1.x, a1.y, a1.z, a1.w};
      float bv[4] = {b.x, b.y, b.z, b.w};
      #pragma unroll
      for (int i = 0; i < 8; i++)
        #pragma unroll
        for (int j = 0; j < 4; j++)
          acc[i][j] += av[i] * bv[j];
    }
    __syncthreads();
  }
  #pragma unroll
  for (int i = 0; i < 8; i++){
    int row = m0 + ty * 8 + i;
    if (row < M)
      *(float4*)&Cm[(size_t)row * HC + n0 + tx * 4] =
        make_float4(acc[i][0], acc[i][1], acc[i][2], acc[i][3]);
  }
}

// ---------------- attention scalars: a_src/a_dst[n,h] = sum_c h[n,h,c]*att[h,c] ----------------

__global__ void att_kernel(const float* __restrict__ h, const float* __restrict__ att_s,
                           const float* __restrict__ att_d, float* __restrict__ a_src,
                           float* __restrict__ a_dst, int N){
  int n = blockIdx.x;
  int t = threadIdx.x;           // t = head*64 + c
  float hv = h[(size_t)n * HC + t];
  float vs = hv * att_s[t];
  float vd = hv * att_d[t];
  #pragma unroll
  for (int off = 32; off >= 1; off >>= 1){
    vs += __shfl_xor(vs, off);
    vd += __shfl_xor(vd, off);
  }
  if ((t & 63) == 0){
    a_src[n * HEADS + (t >> 6)] = vs;
    a_dst[n * HEADS + (t >> 6)] = vd;
  }
}

// ---------------- softmax-weighted aggregation (CSR, one wave per (node, head)) ----------------

__global__ void agg_kernel(const float* __restrict__ h, const float* __restrict__ a_src,
                           const float* __restrict__ a_dst, const int* __restrict__ ptr,
                           const int* __restrict__ csr_src, const float* __restrict__ bias,
                           float* __restrict__ out, int N){
  int n = blockIdx.x;
  int head = threadIdx.x >> 6;
  int lane = threadIdx.x & 63;
  int beg = ptr[n], end = ptr[n + 1];
  float adst = a_dst[n * HEADS + head];
  // pass A: segment max (lane-parallel over edges)
  float m = -1e30f;
  for (int i = beg + lane; i < end; i += 64){
    int s = csr_src[i];
    float e = a_src[s * HEADS + head] + adst;
    e = e > 0.f ? e : 0.2f * e;
    m = fmaxf(m, e);
  }
  #pragma unroll
  for (int off = 32; off >= 1; off >>= 1) m = fmaxf(m, __shfl_xor(m, off));
  // pass B: weighted accumulation, lane = channel
  float acc = 0.f, ss = 0.f;
  for (int i = beg; i < end; ++i){
    int s = csr_src[i];
    float e = a_src[s * HEADS + head] + adst;
    e = e > 0.f ? e : 0.2f * e;
    float wgt = __expf(e - m);
    ss += wgt;
    acc += wgt * h[(size_t)s * HC + head * CH + lane];
  }
  float r = acc / (ss + 1e-16f);
  if (bias) r += bias[head * CH + lane];
  out[(size_t)n * HC + head * CH + lane] = r;
}

// ---------------- mean over heads + bias (layer 2, concat=False) ----------------

__global__ void mean_kernel(const float* __restrict__ t, const float* __restrict__ b2,
                            float* __restrict__ f2, int N){
  int idx = blockIdx.x * blockDim.x + threadIdx.x;
  if (idx >= N * CH) return;
  int n = idx >> 6, c = idx & 63;
  const float* p = &t[(size_t)n * HC];
  f2[idx] = 0.25f * (p[c] + p[CH + c] + p[2 * CH + c] + p[3 * CH + c]) + b2[c];
}

// ---------------- fused MLP head: relu(f2 @ lw0 + lb0) @ lw1 + lb1 ----------------

__global__ void head_kernel(const float* __restrict__ f2, const float* __restrict__ lw0,
                            const float* __restrict__ lb0, const float* __restrict__ lw1,
                            const float* __restrict__ lb1, float* __restrict__ outp, int N){
  int n = blockIdx.x * 4 + (threadIdx.x >> 6);
  if (n >= N) return;
  int lane = threadIdx.x & 63;
  float f = f2[(size_t)n * CH + lane];
  float z0 = lb0[lane], z1 = lb0[64 + lane];
  #pragma unroll
  for (int k = 0; k < 64; k++){
    float fk = __shfl(f, k);
    z0 += fk * lw0[k * 128 + lane];
    z1 += fk * lw0[k * 128 + 64 + lane];
  }
  z0 = fmaxf(z0, 0.f);
  z1 = fmaxf(z1, 0.f);
  #pragma unroll
  for (int i = 0; i < 10; i++){
    float p = z0 * lw1[lane * 10 + i] + z1 * lw1[(64 + lane) * 10 + i];
    #pragma unroll
    for (int off = 32; off >= 1; off >>= 1) p += __shfl_xor(p, off);
    if (lane == 0) outp[(size_t)n * 10 + i] = p + lb1[i];
  }
}

// ---------------- launcher ----------------

extern "C" void kernel_launch(void* const* d_in, const int* in_sizes, int n_in,
                              void* d_out, int out_size, void* d_ws, size_t ws_size,
                              hipStream_t stream) {
  const float* x   = (const float*)d_in[0];
  const int*   ei  = (const int*)d_in[1];
  const float* W0  = (const float*)d_in[2];
  const float* as0 = (const float*)d_in[3];
  const float* ad0 = (const float*)d_in[4];
  const float* b0  = (const float*)d_in[5];
  const float* W1  = (const float*)d_in[6];
  const float* as1 = (const float*)d_in[7];
  const float* ad1 = (const float*)d_in[8];
  const float* b1  = (const float*)d_in[9];
  const float* W2  = (const float*)d_in[10];
  const float* as2 = (const float*)d_in[11];
  const float* ad2 = (const float*)d_in[12];
  const float* b2  = (const float*)d_in[13];
  const float* lw0 = (const float*)d_in[14];
  const float* lb0 = (const float*)d_in[15];
  const float* lw1 = (const float*)d_in[16];
  const float* lb1 = (const float*)d_in[17];
  float* outp = (float*)d_out;

  int N  = in_sizes[0] / 128;
  int E  = in_sizes[1] / 2;
  int ET = E + N;

  char* ws = (char*)d_ws;
  float* F   = (float*)ws; ws += (size_t)N * HC * sizeof(float);
  float* Hb  = (float*)ws; ws += (size_t)N * HC * sizeof(float);
  float* a_s = (float*)ws; ws += (size_t)N * HEADS * sizeof(float);
  float* a_d = (float*)ws; ws += (size_t)N * HEADS * sizeof(float);
  int* cnt   = (int*)ws;   ws += (size_t)N * sizeof(int);
  int* cur   = (int*)ws;   ws += (size_t)N * sizeof(int);
  int* ptrA  = (int*)ws;   ws += (size_t)(N + 1) * sizeof(int);
  int* csr   = (int*)ws;   ws += (size_t)ET * sizeof(int);
  float* f2  = Hb;   // reused after layer-2 aggregation (Hb is dead by then)

  const int* srcArr = ei;
  const int* dstArr = ei + E;

  // CSR build (graph identical every call; ws is re-poisoned so rebuild each call)
  hipMemsetAsync(cnt, 0, (size_t)N * sizeof(int), stream);
  hist_kernel<<<(ET + 255) / 256, 256, 0, stream>>>(dstArr, E, ET, cnt);
  scan_kernel<<<1, 1024, 0, stream>>>(cnt, ptrA, cur, N);
  scatter_kernel<<<(ET + 255) / 256, 256, 0, stream>>>(srcArr, dstArr, E, ET, cur, csr);

  dim3 ggrid((N + 127) / 128, 4);

  // layer 0: 128 -> 4x64, concat
  gemm_kernel<<<ggrid, 256, 0, stream>>>(x, W0, Hb, N, 128);
  att_kernel<<<N, 256, 0, stream>>>(Hb, as0, ad0, a_s, a_d, N);
  agg_kernel<<<N, 256, 0, stream>>>(Hb, a_s, a_d, ptrA, csr, b0, F, N);

  // layer 1: 256 -> 4x64, concat
  gemm_kernel<<<ggrid, 256, 0, stream>>>(F, W1, Hb, N, 256);
  att_kernel<<<N, 256, 0, stream>>>(Hb, as1, ad1, a_s, a_d, N);
  agg_kernel<<<N, 256, 0, stream>>>(Hb, a_s, a_d, ptrA, csr, b1, F, N);

  // layer 2: 256 -> 4x64, mean over heads
  gemm_kernel<<<ggrid, 256, 0, stream>>>(F, W2, Hb, N, 256);
  att_kernel<<<N, 256, 0, stream>>>(Hb, as2, ad2, a_s, a_d, N);
  agg_kernel<<<N, 256, 0, stream>>>(Hb, a_s, a_d, ptrA, csr, nullptr, F, N);  // per-head, no bias
  mean_kernel<<<(N * CH + 255) / 256, 256, 0, stream>>>(F, b2, f2, N);

  // MLP head
  head_kernel<<<(N + 3) / 4, 256, 0, stream>>>(f2, lw0, lb0, lw1, lb1, outp, N);
}

// Round 2
// 999.449 us; speedup vs baseline: 1.3401x; 1.3401x over previous
//
#include <hip/hip_runtime.h>
#include <hip/hip_bf16.h>

#define HEADS 4
#define CH 64
#define HC 256

// ---------------- CSR build ----------------

__global__ void hist_kernel(const int* __restrict__ dst, int E, int ET, int* __restrict__ cnt){
  int e = blockIdx.x * blockDim.x + threadIdx.x;
  if (e >= ET) return;
  int d = (e < E) ? dst[e] : (e - E);   // self-loop edges appended
  atomicAdd(&cnt[d], 1);
}

// parallel scan: per-block sums -> single-block exclusive scan of sums -> final
__global__ void blocksum_kernel(const int* __restrict__ cnt, int N, int* __restrict__ bsum){
  int tid = threadIdx.x;
  int i = blockIdx.x * 256 + tid;
  int v = (i < N) ? cnt[i] : 0;
  #pragma unroll
  for (int off = 32; off >= 1; off >>= 1) v += __shfl_xor(v, off);
  __shared__ int ws[4];
  if ((tid & 63) == 0) ws[tid >> 6] = v;
  __syncthreads();
  if (tid == 0) bsum[blockIdx.x] = ws[0] + ws[1] + ws[2] + ws[3];
}

__global__ void scanb_kernel(int* __restrict__ bsum, int nb){
  __shared__ int buf[256];
  int tid = threadIdx.x;
  int v = (tid < nb) ? bsum[tid] : 0;
  buf[tid] = v;
  __syncthreads();
  #pragma unroll
  for (int off = 1; off < 256; off <<= 1){
    int t = (tid >= off) ? buf[tid - off] : 0;
    __syncthreads();
    buf[tid] += t;
    __syncthreads();
  }
  if (tid < nb) bsum[tid] = buf[tid] - v;  // exclusive
}

__global__ void scanfinal_kernel(const int* __restrict__ cnt, const int* __restrict__ bsum,
                                 int* __restrict__ ptr, int* __restrict__ cur, int N){
  __shared__ int buf[256];
  int tid = threadIdx.x;
  int i = blockIdx.x * 256 + tid;
  int v = (i < N) ? cnt[i] : 0;
  buf[tid] = v;
  __syncthreads();
  #pragma unroll
  for (int off = 1; off < 256; off <<= 1){
    int t = (tid >= off) ? buf[tid - off] : 0;
    __syncthreads();
    buf[tid] += t;
    __syncthreads();
  }
  int exc = buf[tid] - v + bsum[blockIdx.x];
  if (i < N){
    ptr[i] = exc; cur[i] = exc;
    if (i == N - 1) ptr[N] = exc + v;
  }
}

__global__ void scatter_kernel(const int* __restrict__ src, const int* __restrict__ dst,
                               int E, int ET, int* __restrict__ cur, int* __restrict__ csr_src){
  int e = blockIdx.x * blockDim.x + threadIdx.x;
  if (e >= ET) return;
  int s, d;
  if (e < E){ s = src[e]; d = dst[e]; } else { s = e - E; d = e - E; }
  int pos = atomicAdd(&cur[d], 1);
  csr_src[pos] = s;
}

// ---------------- fp32 GEMM 128x128x16 + fused attention-score epilogue ----------------
// C[M,256] = A[M,K] @ B[K,256]; also a_src[m,h]=sum_c C*att_s, a_dst likewise.
// 256 threads; thread (rg=tid>>4, cg=tid&15) computes rows {rg*4+i, 64+rg*4+i},
// cols {cg*4+j, 64+cg*4+j} (split 4+4 keeps LDS b128 reads conflict-free).

__launch_bounds__(256)
__global__ void gemm_att_kernel(const float* __restrict__ A, const float* __restrict__ B,
                                float* __restrict__ Cm,
                                const float* __restrict__ att_s, const float* __restrict__ att_d,
                                float* __restrict__ a_src, float* __restrict__ a_dst,
                                int M, int K){
  __shared__ float As[16][132];
  __shared__ float Bs[16][132];
  int tid = threadIdx.x;
  int rg = tid >> 4, cg = tid & 15;
  int m0 = blockIdx.x * 128, n0 = blockIdx.y * 128;
  int hb = blockIdx.y * 2;            // this block covers heads hb, hb+1

  float acc[2][4][2][4];
  #pragma unroll
  for (int a = 0; a < 2; a++)
    #pragma unroll
    for (int b = 0; b < 4; b++)
      #pragma unroll
      for (int c = 0; c < 2; c++)
        #pragma unroll
        for (int d = 0; d < 4; d++) acc[a][b][c][d] = 0.f;

  for (int k0 = 0; k0 < K; k0 += 16){
    #pragma unroll
    for (int q = 0; q < 2; q++){            // A tile 128x16 = 512 float4
      int idx = q * 256 + tid;
      int ar = idx >> 2, ak4 = idx & 3;
      int gm = m0 + ar;
      float4 v = make_float4(0.f, 0.f, 0.f, 0.f);
      if (gm < M) v = *(const float4*)&A[(size_t)gm * K + k0 + ak4 * 4];
      As[ak4*4+0][ar] = v.x; As[ak4*4+1][ar] = v.y;
      As[ak4*4+2][ar] = v.z; As[ak4*4+3][ar] = v.w;
    }
    #pragma unroll
    for (int q = 0; q < 2; q++){            // B tile 16x128 = 512 float4
      int idx = q * 256 + tid;
      int br = idx >> 5, bc4 = idx & 31;
      *(float4*)&Bs[br][bc4*4] = *(const float4*)&B[(size_t)(k0 + br) * HC + n0 + bc4 * 4];
    }
    __syncthreads();
    #pragma unroll
    for (int k = 0; k < 16; k++){
      float4 a0 = *(float4*)&As[k][rg * 4];
      float4 a1 = *(float4*)&As[k][64 + rg * 4];
      float4 b0 = *(float4*)&Bs[k][cg * 4];
      float4 b1 = *(float4*)&Bs[k][64 + cg * 4];
      float av[2][4] = {{a0.x,a0.y,a0.z,a0.w},{a1.x,a1.y,a1.z,a1.w}};
      float bv[2][4] = {{b0.x,b0.y,b0.z,b0.w},{b1.x,b1.y,b1.z,b1.w}};
      #pragma unroll
      for (int rh = 0; rh < 2; rh++)
        #pragma unroll
        for (int ri = 0; ri < 4; ri++)
          #pragma unroll
          for (int ch = 0; ch < 2; ch++)
            #pragma unroll
            for (int cj = 0; cj < 4; cj++)
              acc[rh][ri][ch][cj] += av[rh][ri] * bv[ch][cj];
    }
    __syncthreads();
  }

  // store C
  #pragma unroll
  for (int rh = 0; rh < 2; rh++)
    #pragma unroll
    for (int ri = 0; ri < 4; ri++){
      int row = m0 + rh * 64 + rg * 4 + ri;
      if (row >= M) continue;
      #pragma unroll
      for (int ch = 0; ch < 2; ch++)
        *(float4*)&Cm[(size_t)row * HC + n0 + ch * 64 + cg * 4] =
          make_float4(acc[rh][ri][ch][0], acc[rh][ri][ch][1],
                      acc[rh][ri][ch][2], acc[rh][ri][ch][3]);
    }

  // fused attention scores: a_src/a_dst[row, hb+ch] = sum_c C*att
  float4 as0 = *(const float4*)&att_s[hb * CH + cg * 4];
  float4 as1 = *(const float4*)&att_s[(hb + 1) * CH + cg * 4];
  float4 ad0 = *(const float4*)&att_d[hb * CH + cg * 4];
  float4 ad1 = *(const float4*)&att_d[(hb + 1) * CH + cg * 4];
  #pragma unroll
  for (int rh = 0; rh < 2; rh++)
    #pragma unroll
    for (int ri = 0; ri < 4; ri++){
      int row = m0 + rh * 64 + rg * 4 + ri;
      float s0 = acc[rh][ri][0][0]*as0.x + acc[rh][ri][0][1]*as0.y + acc[rh][ri][0][2]*as0.z + acc[rh][ri][0][3]*as0.w;
      float s1 = acc[rh][ri][1][0]*as1.x + acc[rh][ri][1][1]*as1.y + acc[rh][ri][1][2]*as1.z + acc[rh][ri][1][3]*as1.w;
      float d0 = acc[rh][ri][0][0]*ad0.x + acc[rh][ri][0][1]*ad0.y + acc[rh][ri][0][2]*ad0.z + acc[rh][ri][0][3]*ad0.w;
      float d1 = acc[rh][ri][1][0]*ad1.x + acc[rh][ri][1][1]*ad1.y + acc[rh][ri][1][2]*ad1.z + acc[rh][ri][1][3]*ad1.w;
      #pragma unroll
      for (int off = 1; off <= 8; off <<= 1){
        s0 += __shfl_xor(s0, off); s1 += __shfl_xor(s1, off);
        d0 += __shfl_xor(d0, off); d1 += __shfl_xor(d1, off);
      }
      if (cg == 0 && row < M){
        a_src[row * HEADS + hb]     = s0;
        a_src[row * HEADS + hb + 1] = s1;
        a_dst[row * HEADS + hb]     = d0;
        a_dst[row * HEADS + hb + 1] = d1;
      }
    }
}

// ---------------- softmax-weighted aggregation (4 edges in flight per wave) ----------------
// block = node, wave = head; lane = eg(2b) x c4(4b): eg = edge subgroup, c4 = channel quad.

__global__ void agg_kernel(const float* __restrict__ h, const float* __restrict__ a_src,
                           const float* __restrict__ a_dst, const int* __restrict__ ptr,
                           const int* __restrict__ csr_src, const float* __restrict__ bias,
                           float* __restrict__ out, int N, int mean_mode,
                           const float* __restrict__ b2){
  __shared__ float sm[HEADS][CH];
  int n = blockIdx.x;
  int head = threadIdx.x >> 6;
  int lane = threadIdx.x & 63;
  int beg = ptr[n], end = ptr[n + 1];
  float adst = a_dst[n * HEADS + head];

  // pass A: segment max, all 64 lanes over edges
  float m = -1e30f;
  for (int i = beg + lane; i < end; i += 64){
    int s = csr_src[i];
    float e = a_src[s * HEADS + head] + adst;
    e = e > 0.f ? e : 0.2f * e;
    m = fmaxf(m, e);
  }
  #pragma unroll
  for (int off = 32; off >= 1; off >>= 1) m = fmaxf(m, __shfl_xor(m, off));

  // pass B: 4 edge-subgroups x 16 channel-quads
  int eg = lane >> 4, c4 = lane & 15;
  float4 acc = make_float4(0.f, 0.f, 0.f, 0.f);
  float ss = 0.f;
  for (int i = beg + eg; i < end; i += 4){
    int s = csr_src[i];
    float e = a_src[s * HEADS + head] + adst;
    e = e > 0.f ? e : 0.2f * e;
    float w = __expf(e - m);
    ss += w;
    float4 hv = *(const float4*)&h[(size_t)s * HC + head * CH + c4 * 4];
    acc.x += w * hv.x; acc.y += w * hv.y; acc.z += w * hv.z; acc.w += w * hv.w;
  }
  #pragma unroll
  for (int off = 16; off <= 32; off <<= 1){
    acc.x += __shfl_xor(acc.x, off); acc.y += __shfl_xor(acc.y, off);
    acc.z += __shfl_xor(acc.z, off); acc.w += __shfl_xor(acc.w, off);
    ss    += __shfl_xor(ss, off);
  }
  float inv = 1.f / (ss + 1e-16f);
  acc.x *= inv; acc.y *= inv; acc.z *= inv; acc.w *= inv;

  if (!mean_mode){
    if (eg == 0){
      float4 bv = *(const float4*)&bias[head * CH + c4 * 4];
      acc.x += bv.x; acc.y += bv.y; acc.z += bv.z; acc.w += bv.w;
      *(float4*)&out[(size_t)n * HC + head * CH + c4 * 4] = acc;
    }
  } else {
    if (eg == 0) *(float4*)&sm[head][c4 * 4] = acc;
    __syncthreads();
    int t = threadIdx.x;
    if (t < CH)
      out[(size_t)n * CH + t] =
        0.25f * (sm[0][t] + sm[1][t] + sm[2][t] + sm[3][t]) + b2[t];
  }
}

// ---------------- fused MLP head: relu(f2 @ lw0 + lb0) @ lw1 + lb1 ----------------

__global__ void head_kernel(const float* __restrict__ f2, const float* __restrict__ lw0,
                            const float* __restrict__ lb0, const float* __restrict__ lw1,
                            const float* __restrict__ lb1, float* __restrict__ outp, int N){
  int n = blockIdx.x * 4 + (threadIdx.x >> 6);
  if (n >= N) return;
  int lane = threadIdx.x & 63;
  float f = f2[(size_t)n * CH + lane];
  float z0 = lb0[lane], z1 = lb0[64 + lane];
  #pragma unroll
  for (int k = 0; k < 64; k++){
    float fk = __shfl(f, k);
    z0 += fk * lw0[k * 128 + lane];
    z1 += fk * lw0[k * 128 + 64 + lane];
  }
  z0 = fmaxf(z0, 0.f);
  z1 = fmaxf(z1, 0.f);
  #pragma unroll
  for (int i = 0; i < 10; i++){
    float p = z0 * lw1[lane * 10 + i] + z1 * lw1[(64 + lane) * 10 + i];
    #pragma unroll
    for (int off = 32; off >= 1; off >>= 1) p += __shfl_xor(p, off);
    if (lane == 0) outp[(size_t)n * 10 + i] = p + lb1[i];
  }
}

// ---------------- launcher ----------------

extern "C" void kernel_launch(void* const* d_in, const int* in_sizes, int n_in,
                              void* d_out, int out_size, void* d_ws, size_t ws_size,
                              hipStream_t stream) {
  const float* x   = (const float*)d_in[0];
  const int*   ei  = (const int*)d_in[1];
  const float* W0  = (const float*)d_in[2];
  const float* as0 = (const float*)d_in[3];
  const float* ad0 = (const float*)d_in[4];
  const float* b0  = (const float*)d_in[5];
  const float* W1  = (const float*)d_in[6];
  const float* as1 = (const float*)d_in[7];
  const float* ad1 = (const float*)d_in[8];
  const float* b1  = (const float*)d_in[9];
  const float* W2  = (const float*)d_in[10];
  const float* as2 = (const float*)d_in[11];
  const float* ad2 = (const float*)d_in[12];
  const float* b2  = (const float*)d_in[13];
  const float* lw0 = (const float*)d_in[14];
  const float* lb0 = (const float*)d_in[15];
  const float* lw1 = (const float*)d_in[16];
  const float* lb1 = (const float*)d_in[17];
  float* outp = (float*)d_out;

  int N  = in_sizes[0] / 128;
  int E  = in_sizes[1] / 2;
  int ET = E + N;
  int nb = (N + 255) / 256;

  char* ws = (char*)d_ws;
  float* F   = (float*)ws; ws += (size_t)N * HC * sizeof(float);
  float* Hb  = (float*)ws; ws += (size_t)N * HC * sizeof(float);
  float* a_s = (float*)ws; ws += (size_t)N * HEADS * sizeof(float);
  float* a_d = (float*)ws; ws += (size_t)N * HEADS * sizeof(float);
  int* cnt   = (int*)ws;   ws += (size_t)N * sizeof(int);
  int* cur   = (int*)ws;   ws += (size_t)N * sizeof(int);
  int* ptrA  = (int*)ws;   ws += (size_t)(N + 1) * sizeof(int);
  int* bsum  = (int*)ws;   ws += (size_t)nb * sizeof(int);
  int* csr   = (int*)ws;   ws += (size_t)ET * sizeof(int);
  float* f2  = F;   // layer-2 mean output reuses F (Hb holds h, still live during agg)

  const int* srcArr = ei;
  const int* dstArr = ei + E;

  // CSR build
  hipMemsetAsync(cnt, 0, (size_t)N * sizeof(int), stream);
  hist_kernel<<<(ET + 255) / 256, 256, 0, stream>>>(dstArr, E, ET, cnt);
  blocksum_kernel<<<nb, 256, 0, stream>>>(cnt, N, bsum);
  scanb_kernel<<<1, 256, 0, stream>>>(bsum, nb);
  scanfinal_kernel<<<nb, 256, 0, stream>>>(cnt, bsum, ptrA, cur, N);
  scatter_kernel<<<(ET + 255) / 256, 256, 0, stream>>>(srcArr, dstArr, E, ET, cur, csr);

  dim3 ggrid((N + 127) / 128, 2);

  // layer 0: 128 -> 4x64, concat
  gemm_att_kernel<<<ggrid, 256, 0, stream>>>(x, W0, Hb, as0, ad0, a_s, a_d, N, 128);
  agg_kernel<<<N, 256, 0, stream>>>(Hb, a_s, a_d, ptrA, csr, b0, F, N, 0, nullptr);

  // layer 1: 256 -> 4x64, concat
  gemm_att_kernel<<<ggrid, 256, 0, stream>>>(F, W1, Hb, as1, ad1, a_s, a_d, N, 256);
  agg_kernel<<<N, 256, 0, stream>>>(Hb, a_s, a_d, ptrA, csr, b1, F, N, 0, nullptr);

  // layer 2: 256 -> 4x64, mean over heads (+b2), written into f2 = F
  gemm_att_kernel<<<ggrid, 256, 0, stream>>>(F, W2, Hb, as2, ad2, a_s, a_d, N, 256);
  agg_kernel<<<N, 256, 0, stream>>>(Hb, a_s, a_d, ptrA, csr, nullptr, f2, N, 1, b2);

  // MLP head
  head_kernel<<<(N + 3) / 4, 256, 0, stream>>>(f2, lw0, lb0, lw1, lb1, outp, N);
}

// Round 3
// 798.982 us; speedup vs baseline: 1.6763x; 1.2509x over previous
//
#include <hip/hip_runtime.h>
#include <hip/hip_bf16.h>

#define HEADS 4
#define CH 64
#define HC 256

typedef __attribute__((ext_vector_type(8))) short short8;
typedef __attribute__((ext_vector_type(4))) float f32x4;

__device__ inline unsigned short f2bf(float f){
  unsigned u = __float_as_uint(f);
  return (unsigned short)((u + 0x7FFF + ((u >> 16) & 1)) >> 16);
}

// ---------------- CSR build ----------------

__global__ void hist_kernel(const int* __restrict__ dst, int E, int ET, int* __restrict__ cnt){
  int e = blockIdx.x * blockDim.x + threadIdx.x;
  if (e >= ET) return;
  int d = (e < E) ? dst[e] : (e - E);   // self-loop edges appended
  atomicAdd(&cnt[d], 1);
}

__global__ void blocksum_kernel(const int* __restrict__ cnt, int N, int* __restrict__ bsum){
  int tid = threadIdx.x;
  int i = blockIdx.x * 256 + tid;
  int v = (i < N) ? cnt[i] : 0;
  #pragma unroll
  for (int off = 32; off >= 1; off >>= 1) v += __shfl_xor(v, off);
  __shared__ int ws[4];
  if ((tid & 63) == 0) ws[tid >> 6] = v;
  __syncthreads();
  if (tid == 0) bsum[blockIdx.x] = ws[0] + ws[1] + ws[2] + ws[3];
}

__global__ void scanb_kernel(int* __restrict__ bsum, int nb){
  __shared__ int buf[256];
  int tid = threadIdx.x;
  int v = (tid < nb) ? bsum[tid] : 0;
  buf[tid] = v;
  __syncthreads();
  #pragma unroll
  for (int off = 1; off < 256; off <<= 1){
    int t = (tid >= off) ? buf[tid - off] : 0;
    __syncthreads();
    buf[tid] += t;
    __syncthreads();
  }
  if (tid < nb) bsum[tid] = buf[tid] - v;  // exclusive
}

__global__ void scanfinal_kernel(const int* __restrict__ cnt, const int* __restrict__ bsum,
                                 int* __restrict__ ptr, int* __restrict__ cur, int N){
  __shared__ int buf[256];
  int tid = threadIdx.x;
  int i = blockIdx.x * 256 + tid;
  int v = (i < N) ? cnt[i] : 0;
  buf[tid] = v;
  __syncthreads();
  #pragma unroll
  for (int off = 1; off < 256; off <<= 1){
    int t = (tid >= off) ? buf[tid - off] : 0;
    __syncthreads();
    buf[tid] += t;
    __syncthreads();
  }
  int exc = buf[tid] - v + bsum[blockIdx.x];
  if (i < N){
    ptr[i] = exc; cur[i] = exc;
    if (i == N - 1) ptr[N] = exc + v;
  }
}

__global__ void scatter_kernel(const int* __restrict__ src, const int* __restrict__ dst,
                               int E, int ET, int* __restrict__ cur, int* __restrict__ csr_src){
  int e = blockIdx.x * blockDim.x + threadIdx.x;
  if (e >= ET) return;
  int s, d;
  if (e < E){ s = src[e]; d = dst[e]; } else { s = e - E; d = e - E; }
  int pos = atomicAdd(&cur[d], 1);
  csr_src[pos] = s;
}

// ---------------- W pre-split: fp32 [K][256] -> bf16 hi/lo transposed [256][K] ----------------

__global__ void wsplit_kernel(const float* __restrict__ W, int K,
                              unsigned short* __restrict__ hiT, unsigned short* __restrict__ loT){
  int idx = blockIdx.x * 256 + threadIdx.x;
  if (idx >= K * HC) return;
  int k = idx >> 8, n = idx & 255;
  float w = W[idx];
  unsigned short hb = f2bf(w);
  float hf = __uint_as_float((unsigned)hb << 16);
  unsigned short lb = f2bf(w - hf);
  hiT[(size_t)n * K + k] = hb;
  loT[(size_t)n * K + k] = lb;
}

// ---------------- MFMA GEMM (3x bf16 split) + fused attention-score epilogue ----------------
// C[M,256] = A[M,K] @ B[K,256].  128x128 block tile, 4 waves, each 64x64.
// mfma_f32_16x16x32_bf16 layouts (HW-verified per guide):
//   A-frag: lane holds A[m = lane&15][k = (lane>>4)*8 + j], j=0..7
//   B-frag: lane holds B[k = (lane>>4)*8 + j][n = lane&15]  (i.e. BT[n][k])
//   C/D:    reg r -> row = (lane>>4)*4 + r, col = lane&15

__launch_bounds__(256, 2)
__global__ void gemm_mfma_kernel(const float* __restrict__ A,
                                 const unsigned short* __restrict__ BhiT,
                                 const unsigned short* __restrict__ BloT,
                                 float* __restrict__ Cm,
                                 const float* __restrict__ att_s, const float* __restrict__ att_d,
                                 float* __restrict__ a_src, float* __restrict__ a_dst,
                                 int M, int K){
  __shared__ unsigned short As_hi[128][40];   // stride 40 bf16 = 80B: 16B-aligned, 2-way banks
  __shared__ unsigned short As_lo[128][40];
  __shared__ unsigned short Bs_hi[128][40];   // BT layout: [n][k]
  __shared__ unsigned short Bs_lo[128][40];

  int tid = threadIdx.x;
  int m0 = blockIdx.x * 128, n0 = blockIdx.y * 128;
  int wave = tid >> 6, lane = tid & 63;
  int wm = (wave >> 1) * 64, wn = (wave & 1) * 64;
  int col = lane & 15, quad = lane >> 4;

  f32x4 acc[4][4];
  #pragma unroll
  for (int a = 0; a < 4; a++)
    #pragma unroll
    for (int b = 0; b < 4; b++)
      acc[a][b] = (f32x4){0.f, 0.f, 0.f, 0.f};

  for (int k0 = 0; k0 < K; k0 += 32){
    // stage A (128x32 fp32 -> hi/lo bf16 fragment layout)
    #pragma unroll
    for (int r = 0; r < 2; r++){
      int id = r * 256 + tid;
      int m = id >> 2, q = id & 3;
      int gm = m0 + m;
      float va[8];
      if (gm < M){
        float4 v0 = *(const float4*)&A[(size_t)gm * K + k0 + q * 8];
        float4 v1 = *(const float4*)&A[(size_t)gm * K + k0 + q * 8 + 4];
        va[0]=v0.x; va[1]=v0.y; va[2]=v0.z; va[3]=v0.w;
        va[4]=v1.x; va[5]=v1.y; va[6]=v1.z; va[7]=v1.w;
      } else {
        #pragma unroll
        for (int j = 0; j < 8; j++) va[j] = 0.f;
      }
      short8 hi8, lo8;
      #pragma unroll
      for (int j = 0; j < 8; j++){
        unsigned short hb = f2bf(va[j]);
        float hf = __uint_as_float((unsigned)hb << 16);
        hi8[j] = (short)hb;
        lo8[j] = (short)f2bf(va[j] - hf);
      }
      *(short8*)&As_hi[m][q * 8] = hi8;
      *(short8*)&As_lo[m][q * 8] = lo8;
    }
    // stage B (pre-split bf16, already transposed [n][K])
    #pragma unroll
    for (int r = 0; r < 2; r++){
      int id = r * 256 + tid;
      int n = id >> 2, q = id & 3;
      size_t g = (size_t)(n0 + n) * K + k0 + q * 8;
      *(short8*)&Bs_hi[n][q * 8] = *(const short8*)&BhiT[g];
      *(short8*)&Bs_lo[n][q * 8] = *(const short8*)&BloT[g];
    }
    __syncthreads();

    short8 af[4][2], bf[4][2];
    #pragma unroll
    for (int t = 0; t < 4; t++){
      af[t][0] = *(const short8*)&As_hi[wm + t * 16 + col][quad * 8];
      af[t][1] = *(const short8*)&As_lo[wm + t * 16 + col][quad * 8];
      bf[t][0] = *(const short8*)&Bs_hi[wn + t * 16 + col][quad * 8];
      bf[t][1] = *(const short8*)&Bs_lo[wn + t * 16 + col][quad * 8];
    }
    #pragma unroll
    for (int mt = 0; mt < 4; mt++)
      #pragma unroll
      for (int nt = 0; nt < 4; nt++){
        acc[mt][nt] = __builtin_amdgcn_mfma_f32_16x16x32_bf16(af[mt][0], bf[nt][0], acc[mt][nt], 0, 0, 0);
        acc[mt][nt] = __builtin_amdgcn_mfma_f32_16x16x32_bf16(af[mt][1], bf[nt][0], acc[mt][nt], 0, 0, 0);
        acc[mt][nt] = __builtin_amdgcn_mfma_f32_16x16x32_bf16(af[mt][0], bf[nt][1], acc[mt][nt], 0, 0, 0);
      }
    __syncthreads();
  }

  // store C
  #pragma unroll
  for (int mt = 0; mt < 4; mt++)
    #pragma unroll
    for (int nt = 0; nt < 4; nt++){
      int colg = n0 + wn + nt * 16 + col;
      #pragma unroll
      for (int r = 0; r < 4; r++){
        int row = m0 + wm + mt * 16 + quad * 4 + r;
        if (row < M) Cm[(size_t)row * HC + colg] = acc[mt][nt][r];
      }
    }

  // fused attention scores; this wave's 64 n-columns == one head
  int head = (n0 + wn) >> 6;
  float asv[4], adv[4];
  #pragma unroll
  for (int nt = 0; nt < 4; nt++){
    asv[nt] = att_s[head * CH + nt * 16 + col];
    adv[nt] = att_d[head * CH + nt * 16 + col];
  }
  #pragma unroll
  for (int mt = 0; mt < 4; mt++){
    float sp[4] = {0.f,0.f,0.f,0.f}, dp[4] = {0.f,0.f,0.f,0.f};
    #pragma unroll
    for (int nt = 0; nt < 4; nt++)
      #pragma unroll
      for (int r = 0; r < 4; r++){
        sp[r] += acc[mt][nt][r] * asv[nt];
        dp[r] += acc[mt][nt][r] * adv[nt];
      }
    #pragma unroll
    for (int off = 1; off <= 8; off <<= 1)
      #pragma unroll
      for (int r = 0; r < 4; r++){
        sp[r] += __shfl_xor(sp[r], off);
        dp[r] += __shfl_xor(dp[r], off);
      }
    if (col == 0){
      #pragma unroll
      for (int r = 0; r < 4; r++){
        int row = m0 + wm + mt * 16 + quad * 4 + r;
        if (row < M){
          a_src[row * HEADS + head] = sp[r];
          a_dst[row * HEADS + head] = dp[r];
        }
      }
    }
  }
}

// ---------------- softmax aggregation: single pass, no max (|e|<~10 safe in fp32) ----------------
// block = node; wave = head; lane = eg(3b) x c8(3b): 8 edges in flight, 8 floats/lane.

__global__ void agg_kernel(const float* __restrict__ h, const float* __restrict__ a_src,
                           const float* __restrict__ a_dst, const int* __restrict__ ptr,
                           const int* __restrict__ csr_src, const float* __restrict__ bias,
                           float* __restrict__ out, int N, int mean_mode,
                           const float* __restrict__ b2){
  __shared__ float sm[HEADS][CH];
  int n = blockIdx.x;
  int head = threadIdx.x >> 6;
  int lane = threadIdx.x & 63;
  int eg = lane >> 3, c8 = lane & 7;
  int beg = ptr[n], end = ptr[n + 1];
  float adst = a_dst[n * HEADS + head];

  float acc[8] = {0.f,0.f,0.f,0.f,0.f,0.f,0.f,0.f};
  float ss = 0.f;
  for (int i = beg + eg; i < end; i += 8){
    int s = csr_src[i];
    float e = a_src[s * HEADS + head] + adst;
    e = e > 0.f ? e : 0.2f * e;
    float w = __expf(e);
    const float* hp = &h[(size_t)s * HC + head * CH + c8 * 8];
    float4 h0 = *(const float4*)hp;
    float4 h1 = *(const float4*)(hp + 4);
    acc[0] += w * h0.x; acc[1] += w * h0.y; acc[2] += w * h0.z; acc[3] += w * h0.w;
    acc[4] += w * h1.x; acc[5] += w * h1.y; acc[6] += w * h1.z; acc[7] += w * h1.w;
    ss += w;
  }
  #pragma unroll
  for (int off = 8; off <= 32; off <<= 1){
    #pragma unroll
    for (int j = 0; j < 8; j++) acc[j] += __shfl_xor(acc[j], off);
    ss += __shfl_xor(ss, off);
  }
  float inv = 1.f / (ss + 1e-16f);
  #pragma unroll
  for (int j = 0; j < 8; j++) acc[j] *= inv;

  if (!mean_mode){
    if (eg == 0){
      float* op = &out[(size_t)n * HC + head * CH + c8 * 8];
      const float* bp = &bias[head * CH + c8 * 8];
      #pragma unroll
      for (int j = 0; j < 8; j++) op[j] = acc[j] + bp[j];
    }
  } else {
    if (eg == 0){
      #pragma unroll
      for (int j = 0; j < 8; j++) sm[head][c8 * 8 + j] = acc[j];
    }
    __syncthreads();
    int t = threadIdx.x;
    if (t < CH)
      out[(size_t)n * CH + t] =
        0.25f * (sm[0][t] + sm[1][t] + sm[2][t] + sm[3][t]) + b2[t];
  }
}

// ---------------- fused MLP head ----------------

__global__ void head_kernel(const float* __restrict__ f2, const float* __restrict__ lw0,
                            const float* __restrict__ lb0, const float* __restrict__ lw1,
                            const float* __restrict__ lb1, float* __restrict__ outp, int N){
  int n = blockIdx.x * 4 + (threadIdx.x >> 6);
  if (n >= N) return;
  int lane = threadIdx.x & 63;
  float f = f2[(size_t)n * CH + lane];
  float z0 = lb0[lane], z1 = lb0[64 + lane];
  #pragma unroll
  for (int k = 0; k < 64; k++){
    float fk = __shfl(f, k);
    z0 += fk * lw0[k * 128 + lane];
    z1 += fk * lw0[k * 128 + 64 + lane];
  }
  z0 = fmaxf(z0, 0.f);
  z1 = fmaxf(z1, 0.f);
  #pragma unroll
  for (int i = 0; i < 10; i++){
    float p = z0 * lw1[lane * 10 + i] + z1 * lw1[(64 + lane) * 10 + i];
    #pragma unroll
    for (int off = 32; off >= 1; off >>= 1) p += __shfl_xor(p, off);
    if (lane == 0) outp[(size_t)n * 10 + i] = p + lb1[i];
  }
}

// ---------------- launcher ----------------

extern "C" void kernel_launch(void* const* d_in, const int* in_sizes, int n_in,
                              void* d_out, int out_size, void* d_ws, size_t ws_size,
                              hipStream_t stream) {
  const float* x   = (const float*)d_in[0];
  const int*   ei  = (const int*)d_in[1];
  const float* W0  = (const float*)d_in[2];
  const float* as0 = (const float*)d_in[3];
  const float* ad0 = (const float*)d_in[4];
  const float* b0  = (const float*)d_in[5];
  const float* W1  = (const float*)d_in[6];
  const float* as1 = (const float*)d_in[7];
  const float* ad1 = (const float*)d_in[8];
  const float* b1  = (const float*)d_in[9];
  const float* W2  = (const float*)d_in[10];
  const float* as2 = (const float*)d_in[11];
  const float* ad2 = (const float*)d_in[12];
  const float* b2  = (const float*)d_in[13];
  const float* lw0 = (const float*)d_in[14];
  const float* lb0 = (const float*)d_in[15];
  const float* lw1 = (const float*)d_in[16];
  const float* lb1 = (const float*)d_in[17];
  float* outp = (float*)d_out;

  int N  = in_sizes[0] / 128;
  int E  = in_sizes[1] / 2;
  int ET = E + N;
  int nb = (N + 255) / 256;

  char* ws = (char*)d_ws;
  float* F   = (float*)ws; ws += (size_t)N * HC * sizeof(float);
  float* Hb  = (float*)ws; ws += (size_t)N * HC * sizeof(float);
  float* a_s = (float*)ws; ws += (size_t)N * HEADS * sizeof(float);
  float* a_d = (float*)ws; ws += (size_t)N * HEADS * sizeof(float);
  int* cnt   = (int*)ws;   ws += (size_t)N * sizeof(int);
  int* cur   = (int*)ws;   ws += (size_t)N * sizeof(int);
  int* ptrA  = (int*)ws;   ws += (size_t)(N + 1) * sizeof(int);
  int* bsum  = (int*)ws;   ws += (size_t)nb * sizeof(int);
  int* csr   = (int*)ws;   ws += (size_t)ET * sizeof(int);
  unsigned short* w0hi = (unsigned short*)ws; ws += (size_t)128 * HC * 2;
  unsigned short* w0lo = (unsigned short*)ws; ws += (size_t)128 * HC * 2;
  unsigned short* w1hi = (unsigned short*)ws; ws += (size_t)HC * HC * 2;
  unsigned short* w1lo = (unsigned short*)ws; ws += (size_t)HC * HC * 2;
  unsigned short* w2hi = (unsigned short*)ws; ws += (size_t)HC * HC * 2;
  unsigned short* w2lo = (unsigned short*)ws; ws += (size_t)HC * HC * 2;
  float* f2  = F;   // layer-2 mean output reuses F (Hb holds h, still live during agg)

  const int* srcArr = ei;
  const int* dstArr = ei + E;

  // CSR build
  hipMemsetAsync(cnt, 0, (size_t)N * sizeof(int), stream);
  hist_kernel<<<(ET + 255) / 256, 256, 0, stream>>>(dstArr, E, ET, cnt);
  blocksum_kernel<<<nb, 256, 0, stream>>>(cnt, N, bsum);
  scanb_kernel<<<1, 256, 0, stream>>>(bsum, nb);
  scanfinal_kernel<<<nb, 256, 0, stream>>>(cnt, bsum, ptrA, cur, N);
  scatter_kernel<<<(ET + 255) / 256, 256, 0, stream>>>(srcArr, dstArr, E, ET, cur, csr);

  // W splits (hi/lo bf16, transposed)
  wsplit_kernel<<<(128 * HC + 255) / 256, 256, 0, stream>>>(W0, 128, w0hi, w0lo);
  wsplit_kernel<<<(HC * HC + 255) / 256, 256, 0, stream>>>(W1, HC, w1hi, w1lo);
  wsplit_kernel<<<(HC * HC + 255) / 256, 256, 0, stream>>>(W2, HC, w2hi, w2lo);

  dim3 ggrid((N + 127) / 128, 2);

  // layer 0: 128 -> 4x64, concat
  gemm_mfma_kernel<<<ggrid, 256, 0, stream>>>(x, w0hi, w0lo, Hb, as0, ad0, a_s, a_d, N, 128);
  agg_kernel<<<N, 256, 0, stream>>>(Hb, a_s, a_d, ptrA, csr, b0, F, N, 0, nullptr);

  // layer 1: 256 -> 4x64, concat
  gemm_mfma_kernel<<<ggrid, 256, 0, stream>>>(F, w1hi, w1lo, Hb, as1, ad1, a_s, a_d, N, HC);
  agg_kernel<<<N, 256, 0, stream>>>(Hb, a_s, a_d, ptrA, csr, b1, F, N, 0, nullptr);

  // layer 2: 256 -> 4x64, mean over heads (+b2)
  gemm_mfma_kernel<<<ggrid, 256, 0, stream>>>(F, w2hi, w2lo, Hb, as2, ad2, a_s, a_d, N, HC);
  agg_kernel<<<N, 256, 0, stream>>>(Hb, a_s, a_d, ptrA, csr, nullptr, f2, N, 1, b2);

  // MLP head
  head_kernel<<<(N + 3) / 4, 256, 0, stream>>>(f2, lw0, lb0, lw1, lb1, outp, N);
}

// Round 4
// 692.445 us; speedup vs baseline: 1.9342x; 1.1539x over previous
//
#include <hip/hip_runtime.h>
#include <hip/hip_bf16.h>

#define HEADS 4
#define CH 64
#define HC 256

typedef __attribute__((ext_vector_type(8))) short short8;
typedef __attribute__((ext_vector_type(4))) float f32x4;
typedef __attribute__((ext_vector_type(8))) _Float16 half8;

__device__ inline unsigned short f2bf(float f){
  unsigned u = __float_as_uint(f);
  return (unsigned short)((u + 0x7FFF + ((u >> 16) & 1)) >> 16);
}

// ---------------- CSR build ----------------

__global__ void hist_kernel(const int* __restrict__ dst, int E, int ET, int* __restrict__ cnt){
  int e = blockIdx.x * blockDim.x + threadIdx.x;
  if (e >= ET) return;
  int d = (e < E) ? dst[e] : (e - E);   // self-loop edges appended
  atomicAdd(&cnt[d], 1);
}

__global__ void blocksum_kernel(const int* __restrict__ cnt, int N, int* __restrict__ bsum){
  int tid = threadIdx.x;
  int i = blockIdx.x * 256 + tid;
  int v = (i < N) ? cnt[i] : 0;
  #pragma unroll
  for (int off = 32; off >= 1; off >>= 1) v += __shfl_xor(v, off);
  __shared__ int ws[4];
  if ((tid & 63) == 0) ws[tid >> 6] = v;
  __syncthreads();
  if (tid == 0) bsum[blockIdx.x] = ws[0] + ws[1] + ws[2] + ws[3];
}

__global__ void scanb_kernel(int* __restrict__ bsum, int nb){
  __shared__ int buf[256];
  int tid = threadIdx.x;
  int v = (tid < nb) ? bsum[tid] : 0;
  buf[tid] = v;
  __syncthreads();
  #pragma unroll
  for (int off = 1; off < 256; off <<= 1){
    int t = (tid >= off) ? buf[tid - off] : 0;
    __syncthreads();
    buf[tid] += t;
    __syncthreads();
  }
  if (tid < nb) bsum[tid] = buf[tid] - v;  // exclusive
}

__global__ void scanfinal_kernel(const int* __restrict__ cnt, const int* __restrict__ bsum,
                                 int* __restrict__ ptr, int* __restrict__ cur, int N){
  __shared__ int buf[256];
  int tid = threadIdx.x;
  int i = blockIdx.x * 256 + tid;
  int v = (i < N) ? cnt[i] : 0;
  buf[tid] = v;
  __syncthreads();
  #pragma unroll
  for (int off = 1; off < 256; off <<= 1){
    int t = (tid >= off) ? buf[tid - off] : 0;
    __syncthreads();
    buf[tid] += t;
    __syncthreads();
  }
  int exc = buf[tid] - v + bsum[blockIdx.x];
  if (i < N){
    ptr[i] = exc; cur[i] = exc;
    if (i == N - 1) ptr[N] = exc + v;
  }
}

__global__ void scatter_kernel(const int* __restrict__ src, const int* __restrict__ dst,
                               int E, int ET, int* __restrict__ cur, int* __restrict__ csr_src){
  int e = blockIdx.x * blockDim.x + threadIdx.x;
  if (e >= ET) return;
  int s, d;
  if (e < E){ s = src[e]; d = dst[e]; } else { s = e - E; d = e - E; }
  int pos = atomicAdd(&cur[d], 1);
  csr_src[pos] = s;
}

// ---------------- W pre-split (all 3 layers in one launch) ----------------
// fp32 [K][256] -> bf16 hi/lo transposed [256][K]

__global__ void wsplit_kernel(const float* __restrict__ W0, unsigned short* __restrict__ h0,
                              unsigned short* __restrict__ l0,
                              const float* __restrict__ W1, unsigned short* __restrict__ h1,
                              unsigned short* __restrict__ l1,
                              const float* __restrict__ W2, unsigned short* __restrict__ h2,
                              unsigned short* __restrict__ l2){
  int idx = blockIdx.x * 256 + threadIdx.x;
  const float* W; unsigned short *hi, *lo; int K;
  if (idx < 128 * HC){ W = W0; hi = h0; lo = l0; K = 128; }
  else if (idx < (128 + 256) * HC){ idx -= 128 * HC; W = W1; hi = h1; lo = l1; K = 256; }
  else { idx -= (128 + 256) * HC; W = W2; hi = h2; lo = l2; K = 256; }
  int k = idx >> 8, n = idx & 255;
  float w = W[idx];
  unsigned short hb = f2bf(w);
  float hf = __uint_as_float((unsigned)hb << 16);
  unsigned short lb = f2bf(w - hf);
  hi[(size_t)n * K + k] = hb;
  lo[(size_t)n * K + k] = lb;
}

// ---------------- MFMA GEMM (3x bf16 split), fp16 C output + fused att-score epilogue ----------------
// C[M,256] = A[M,K] @ B[K,256].  128x128 block tile, 4 waves, each 64x64.
// mfma_f32_16x16x32_bf16: A-frag lane: A[m=lane&15][k=(lane>>4)*8+j];
// B-frag lane: B[k=(lane>>4)*8+j][n=lane&15]; C/D: reg r -> row=(lane>>4)*4+r, col=lane&15.

__launch_bounds__(256, 2)
__global__ void gemm_mfma_kernel(const float* __restrict__ A,
                                 const unsigned short* __restrict__ BhiT,
                                 const unsigned short* __restrict__ BloT,
                                 _Float16* __restrict__ Cm,
                                 const float* __restrict__ att_s, const float* __restrict__ att_d,
                                 float* __restrict__ a_src, float* __restrict__ a_dst,
                                 int M, int K){
  __shared__ unsigned short As_hi[128][40];   // stride 40 bf16 = 80B: 16B-aligned, 2-way banks
  __shared__ unsigned short As_lo[128][40];
  __shared__ unsigned short Bs_hi[128][40];   // BT layout: [n][k]
  __shared__ unsigned short Bs_lo[128][40];

  int tid = threadIdx.x;
  int m0 = blockIdx.x * 128, n0 = blockIdx.y * 128;
  int wave = tid >> 6, lane = tid & 63;
  int wm = (wave >> 1) * 64, wn = (wave & 1) * 64;
  int col = lane & 15, quad = lane >> 4;

  f32x4 acc[4][4];
  #pragma unroll
  for (int a = 0; a < 4; a++)
    #pragma unroll
    for (int b = 0; b < 4; b++)
      acc[a][b] = (f32x4){0.f, 0.f, 0.f, 0.f};

  for (int k0 = 0; k0 < K; k0 += 32){
    // stage A (128x32 fp32 -> hi/lo bf16 fragment layout)
    #pragma unroll
    for (int r = 0; r < 2; r++){
      int id = r * 256 + tid;
      int m = id >> 2, q = id & 3;
      int gm = m0 + m;
      float va[8];
      if (gm < M){
        float4 v0 = *(const float4*)&A[(size_t)gm * K + k0 + q * 8];
        float4 v1 = *(const float4*)&A[(size_t)gm * K + k0 + q * 8 + 4];
        va[0]=v0.x; va[1]=v0.y; va[2]=v0.z; va[3]=v0.w;
        va[4]=v1.x; va[5]=v1.y; va[6]=v1.z; va[7]=v1.w;
      } else {
        #pragma unroll
        for (int j = 0; j < 8; j++) va[j] = 0.f;
      }
      short8 hi8, lo8;
      #pragma unroll
      for (int j = 0; j < 8; j++){
        unsigned short hb = f2bf(va[j]);
        float hf = __uint_as_float((unsigned)hb << 16);
        hi8[j] = (short)hb;
        lo8[j] = (short)f2bf(va[j] - hf);
      }
      *(short8*)&As_hi[m][q * 8] = hi8;
      *(short8*)&As_lo[m][q * 8] = lo8;
    }
    // stage B (pre-split bf16, already transposed [n][K])
    #pragma unroll
    for (int r = 0; r < 2; r++){
      int id = r * 256 + tid;
      int n = id >> 2, q = id & 3;
      size_t g = (size_t)(n0 + n) * K + k0 + q * 8;
      *(short8*)&Bs_hi[n][q * 8] = *(const short8*)&BhiT[g];
      *(short8*)&Bs_lo[n][q * 8] = *(const short8*)&BloT[g];
    }
    __syncthreads();

    short8 af[4][2], bf[4][2];
    #pragma unroll
    for (int t = 0; t < 4; t++){
      af[t][0] = *(const short8*)&As_hi[wm + t * 16 + col][quad * 8];
      af[t][1] = *(const short8*)&As_lo[wm + t * 16 + col][quad * 8];
      bf[t][0] = *(const short8*)&Bs_hi[wn + t * 16 + col][quad * 8];
      bf[t][1] = *(const short8*)&Bs_lo[wn + t * 16 + col][quad * 8];
    }
    #pragma unroll
    for (int mt = 0; mt < 4; mt++)
      #pragma unroll
      for (int nt = 0; nt < 4; nt++){
        acc[mt][nt] = __builtin_amdgcn_mfma_f32_16x16x32_bf16(af[mt][0], bf[nt][0], acc[mt][nt], 0, 0, 0);
        acc[mt][nt] = __builtin_amdgcn_mfma_f32_16x16x32_bf16(af[mt][1], bf[nt][0], acc[mt][nt], 0, 0, 0);
        acc[mt][nt] = __builtin_amdgcn_mfma_f32_16x16x32_bf16(af[mt][0], bf[nt][1], acc[mt][nt], 0, 0, 0);
      }
    __syncthreads();
  }

  // store C as fp16
  #pragma unroll
  for (int mt = 0; mt < 4; mt++)
    #pragma unroll
    for (int nt = 0; nt < 4; nt++){
      int colg = n0 + wn + nt * 16 + col;
      #pragma unroll
      for (int r = 0; r < 4; r++){
        int row = m0 + wm + mt * 16 + quad * 4 + r;
        if (row < M) Cm[(size_t)row * HC + colg] = (_Float16)acc[mt][nt][r];
      }
    }

  // fused attention scores; this wave's 64 n-columns == one head
  int head = (n0 + wn) >> 6;
  float asv[4], adv[4];
  #pragma unroll
  for (int nt = 0; nt < 4; nt++){
    asv[nt] = att_s[head * CH + nt * 16 + col];
    adv[nt] = att_d[head * CH + nt * 16 + col];
  }
  #pragma unroll
  for (int mt = 0; mt < 4; mt++){
    float sp[4] = {0.f,0.f,0.f,0.f}, dp[4] = {0.f,0.f,0.f,0.f};
    #pragma unroll
    for (int nt = 0; nt < 4; nt++)
      #pragma unroll
      for (int r = 0; r < 4; r++){
        sp[r] += acc[mt][nt][r] * asv[nt];
        dp[r] += acc[mt][nt][r] * adv[nt];
      }
    #pragma unroll
    for (int off = 1; off <= 8; off <<= 1)
      #pragma unroll
      for (int r = 0; r < 4; r++){
        sp[r] += __shfl_xor(sp[r], off);
        dp[r] += __shfl_xor(dp[r], off);
      }
    if (col == 0){
      #pragma unroll
      for (int r = 0; r < 4; r++){
        int row = m0 + wm + mt * 16 + quad * 4 + r;
        if (row < M){
          a_src[row * HEADS + head] = sp[r];
          a_dst[row * HEADS + head] = dp[r];
        }
      }
    }
  }
}

// ---------------- softmax aggregation: fp16 h gather, single pass, no max ----------------
// block = node; wave = head; lane = eg(3b) x c8(3b): 8 edges in flight, 16B/lane gather.

__global__ void agg_kernel(const _Float16* __restrict__ h, const float* __restrict__ a_src,
                           const float* __restrict__ a_dst, const int* __restrict__ ptr,
                           const int* __restrict__ csr_src, const float* __restrict__ bias,
                           float* __restrict__ out, int N, int mean_mode,
                           const float* __restrict__ b2){
  __shared__ float sm[HEADS][CH];
  int n = blockIdx.x;
  int head = threadIdx.x >> 6;
  int lane = threadIdx.x & 63;
  int eg = lane >> 3, c8 = lane & 7;
  int beg = ptr[n], end = ptr[n + 1];
  float adst = a_dst[n * HEADS + head];

  float acc[8] = {0.f,0.f,0.f,0.f,0.f,0.f,0.f,0.f};
  float ss = 0.f;
  for (int i = beg + eg; i < end; i += 8){
    int s = csr_src[i];
    float e = a_src[s * HEADS + head] + adst;
    e = e > 0.f ? e : 0.2f * e;
    float w = __expf(e);
    half8 hv = *(const half8*)&h[(size_t)s * HC + head * CH + c8 * 8];
    #pragma unroll
    for (int j = 0; j < 8; j++) acc[j] += w * (float)hv[j];
    ss += w;
  }
  #pragma unroll
  for (int off = 8; off <= 32; off <<= 1){
    #pragma unroll
    for (int j = 0; j < 8; j++) acc[j] += __shfl_xor(acc[j], off);
    ss += __shfl_xor(ss, off);
  }
  float inv = 1.f / (ss + 1e-16f);
  #pragma unroll
  for (int j = 0; j < 8; j++) acc[j] *= inv;

  if (!mean_mode){
    if (eg == 0){
      float* op = &out[(size_t)n * HC + head * CH + c8 * 8];
      const float* bp = &bias[head * CH + c8 * 8];
      #pragma unroll
      for (int j = 0; j < 8; j++) op[j] = acc[j] + bp[j];
    }
  } else {
    if (eg == 0){
      #pragma unroll
      for (int j = 0; j < 8; j++) sm[head][c8 * 8 + j] = acc[j];
    }
    __syncthreads();
    int t = threadIdx.x;
    if (t < CH)
      out[(size_t)n * CH + t] =
        0.25f * (sm[0][t] + sm[1][t] + sm[2][t] + sm[3][t]) + b2[t];
  }
}

// ---------------- fused MLP head ----------------

__global__ void head_kernel(const float* __restrict__ f2, const float* __restrict__ lw0,
                            const float* __restrict__ lb0, const float* __restrict__ lw1,
                            const float* __restrict__ lb1, float* __restrict__ outp, int N){
  int n = blockIdx.x * 4 + (threadIdx.x >> 6);
  if (n >= N) return;
  int lane = threadIdx.x & 63;
  float f = f2[(size_t)n * CH + lane];
  float z0 = lb0[lane], z1 = lb0[64 + lane];
  #pragma unroll
  for (int k = 0; k < 64; k++){
    float fk = __shfl(f, k);
    z0 += fk * lw0[k * 128 + lane];
    z1 += fk * lw0[k * 128 + 64 + lane];
  }
  z0 = fmaxf(z0, 0.f);
  z1 = fmaxf(z1, 0.f);
  #pragma unroll
  for (int i = 0; i < 10; i++){
    float p = z0 * lw1[lane * 10 + i] + z1 * lw1[(64 + lane) * 10 + i];
    #pragma unroll
    for (int off = 32; off >= 1; off >>= 1) p += __shfl_xor(p, off);
    if (lane == 0) outp[(size_t)n * 10 + i] = p + lb1[i];
  }
}

// ---------------- launcher ----------------

extern "C" void kernel_launch(void* const* d_in, const int* in_sizes, int n_in,
                              void* d_out, int out_size, void* d_ws, size_t ws_size,
                              hipStream_t stream) {
  const float* x   = (const float*)d_in[0];
  const int*   ei  = (const int*)d_in[1];
  const float* W0  = (const float*)d_in[2];
  const float* as0 = (const float*)d_in[3];
  const float* ad0 = (const float*)d_in[4];
  const float* b0  = (const float*)d_in[5];
  const float* W1  = (const float*)d_in[6];
  const float* as1 = (const float*)d_in[7];
  const float* ad1 = (const float*)d_in[8];
  const float* b1  = (const float*)d_in[9];
  const float* W2  = (const float*)d_in[10];
  const float* as2 = (const float*)d_in[11];
  const float* ad2 = (const float*)d_in[12];
  const float* b2  = (const float*)d_in[13];
  const float* lw0 = (const float*)d_in[14];
  const float* lb0 = (const float*)d_in[15];
  const float* lw1 = (const float*)d_in[16];
  const float* lb1 = (const float*)d_in[17];
  float* outp = (float*)d_out;

  int N  = in_sizes[0] / 128;
  int E  = in_sizes[1] / 2;
  int ET = E + N;
  int nb = (N + 255) / 256;

  char* ws = (char*)d_ws;
  float* F       = (float*)ws;    ws += (size_t)N * HC * sizeof(float);
  _Float16* Hb   = (_Float16*)ws; ws += (size_t)N * HC * sizeof(_Float16);
  float* a_s = (float*)ws; ws += (size_t)N * HEADS * sizeof(float);
  float* a_d = (float*)ws; ws += (size_t)N * HEADS * sizeof(float);
  int* cnt   = (int*)ws;   ws += (size_t)N * sizeof(int);
  int* cur   = (int*)ws;   ws += (size_t)N * sizeof(int);
  int* ptrA  = (int*)ws;   ws += (size_t)(N + 1) * sizeof(int);
  int* bsum  = (int*)ws;   ws += (size_t)nb * sizeof(int);
  int* csr   = (int*)ws;   ws += (size_t)ET * sizeof(int);
  unsigned short* w0hi = (unsigned short*)ws; ws += (size_t)128 * HC * 2;
  unsigned short* w0lo = (unsigned short*)ws; ws += (size_t)128 * HC * 2;
  unsigned short* w1hi = (unsigned short*)ws; ws += (size_t)HC * HC * 2;
  unsigned short* w1lo = (unsigned short*)ws; ws += (size_t)HC * HC * 2;
  unsigned short* w2hi = (unsigned short*)ws; ws += (size_t)HC * HC * 2;
  unsigned short* w2lo = (unsigned short*)ws; ws += (size_t)HC * HC * 2;
  float* f2  = F;   // layer-2 mean output reuses F (Hb holds h, still live during agg)

  const int* srcArr = ei;
  const int* dstArr = ei + E;

  // CSR build
  hipMemsetAsync(cnt, 0, (size_t)N * sizeof(int), stream);
  hist_kernel<<<(ET + 255) / 256, 256, 0, stream>>>(dstArr, E, ET, cnt);
  blocksum_kernel<<<nb, 256, 0, stream>>>(cnt, N, bsum);
  scanb_kernel<<<1, 256, 0, stream>>>(bsum, nb);
  scanfinal_kernel<<<nb, 256, 0, stream>>>(cnt, bsum, ptrA, cur, N);
  scatter_kernel<<<(ET + 255) / 256, 256, 0, stream>>>(srcArr, dstArr, E, ET, cur, csr);

  // W splits (hi/lo bf16, transposed) — one launch for all 3 layers
  wsplit_kernel<<<((128 + 256 + 256) * HC) / 256, 256, 0, stream>>>(
      W0, w0hi, w0lo, W1, w1hi, w1lo, W2, w2hi, w2lo);

  dim3 ggrid((N + 127) / 128, 2);

  // layer 0: 128 -> 4x64, concat
  gemm_mfma_kernel<<<ggrid, 256, 0, stream>>>(x, w0hi, w0lo, Hb, as0, ad0, a_s, a_d, N, 128);
  agg_kernel<<<N, 256, 0, stream>>>(Hb, a_s, a_d, ptrA, csr, b0, F, N, 0, nullptr);

  // layer 1: 256 -> 4x64, concat
  gemm_mfma_kernel<<<ggrid, 256, 0, stream>>>(F, w1hi, w1lo, Hb, as1, ad1, a_s, a_d, N, HC);
  agg_kernel<<<N, 256, 0, stream>>>(Hb, a_s, a_d, ptrA, csr, b1, F, N, 0, nullptr);

  // layer 2: 256 -> 4x64, mean over heads (+b2)
  gemm_mfma_kernel<<<ggrid, 256, 0, stream>>>(F, w2hi, w2lo, Hb, as2, ad2, a_s, a_d, N, HC);
  agg_kernel<<<N, 256, 0, stream>>>(Hb, a_s, a_d, ptrA, csr, nullptr, f2, N, 1, b2);

  // MLP head
  head_kernel<<<(N + 3) / 4, 256, 0, stream>>>(f2, lw0, lb0, lw1, lb1, outp, N);
}

// Round 5
// 595.762 us; speedup vs baseline: 2.2481x; 1.1623x over previous
//
#include <hip/hip_runtime.h>
#include <hip/hip_bf16.h>

#define HEADS 4
#define CH 64
#define HC 256

typedef __attribute__((ext_vector_type(8))) short short8;
typedef __attribute__((ext_vector_type(4))) float f32x4;
typedef __attribute__((ext_vector_type(8))) _Float16 half8;

__device__ inline unsigned short f2bf(float f){
  unsigned u = __float_as_uint(f);
  return (unsigned short)((u + 0x7FFF + ((u >> 16) & 1)) >> 16);
}

// ---------------- CSR build ----------------

__global__ void hist_kernel(const int* __restrict__ dst, int E, int ET, int* __restrict__ cnt){
  int e = blockIdx.x * blockDim.x + threadIdx.x;
  if (e >= ET) return;
  int d = (e < E) ? dst[e] : (e - E);   // self-loop edges appended
  atomicAdd(&cnt[d], 1);
}

__global__ void blocksum_kernel(const int* __restrict__ cnt, int N, int* __restrict__ bsum){
  int tid = threadIdx.x;
  int i = blockIdx.x * 256 + tid;
  int v = (i < N) ? cnt[i] : 0;
  #pragma unroll
  for (int off = 32; off >= 1; off >>= 1) v += __shfl_xor(v, off);
  __shared__ int ws[4];
  if ((tid & 63) == 0) ws[tid >> 6] = v;
  __syncthreads();
  if (tid == 0) bsum[blockIdx.x] = ws[0] + ws[1] + ws[2] + ws[3];
}

__global__ void scanb_kernel(int* __restrict__ bsum, int nb){
  __shared__ int buf[256];
  int tid = threadIdx.x;
  int v = (tid < nb) ? bsum[tid] : 0;
  buf[tid] = v;
  __syncthreads();
  #pragma unroll
  for (int off = 1; off < 256; off <<= 1){
    int t = (tid >= off) ? buf[tid - off] : 0;
    __syncthreads();
    buf[tid] += t;
    __syncthreads();
  }
  if (tid < nb) bsum[tid] = buf[tid] - v;  // exclusive
}

__global__ void scanfinal_kernel(const int* __restrict__ cnt, const int* __restrict__ bsum,
                                 int* __restrict__ ptr, int* __restrict__ cur, int N){
  __shared__ int buf[256];
  int tid = threadIdx.x;
  int i = blockIdx.x * 256 + tid;
  int v = (i < N) ? cnt[i] : 0;
  buf[tid] = v;
  __syncthreads();
  #pragma unroll
  for (int off = 1; off < 256; off <<= 1){
    int t = (tid >= off) ? buf[tid - off] : 0;
    __syncthreads();
    buf[tid] += t;
    __syncthreads();
  }
  int exc = buf[tid] - v + bsum[blockIdx.x];
  if (i < N){
    ptr[i] = exc; cur[i] = exc;
    if (i == N - 1) ptr[N] = exc + v;
  }
}

__global__ void scatter_kernel(const int* __restrict__ src, const int* __restrict__ dst,
                               int E, int ET, int* __restrict__ cur, int* __restrict__ csr_src){
  int e = blockIdx.x * blockDim.x + threadIdx.x;
  if (e >= ET) return;
  int s, d;
  if (e < E){ s = src[e]; d = dst[e]; } else { s = e - E; d = e - E; }
  int pos = atomicAdd(&cur[d], 1);
  csr_src[pos] = s;
}

// ---------------- W pre-split (all 3 layers in one launch) ----------------
// fp32 [K][256] -> bf16 hi/lo transposed [256][K]

__global__ void wsplit_kernel(const float* __restrict__ W0, unsigned short* __restrict__ h0,
                              unsigned short* __restrict__ l0,
                              const float* __restrict__ W1, unsigned short* __restrict__ h1,
                              unsigned short* __restrict__ l1,
                              const float* __restrict__ W2, unsigned short* __restrict__ h2,
                              unsigned short* __restrict__ l2){
  int idx = blockIdx.x * 256 + threadIdx.x;
  const float* W; unsigned short *hi, *lo; int K;
  if (idx < 128 * HC){ W = W0; hi = h0; lo = l0; K = 128; }
  else if (idx < (128 + 256) * HC){ idx -= 128 * HC; W = W1; hi = h1; lo = l1; K = 256; }
  else { idx -= (128 + 256) * HC; W = W2; hi = h2; lo = l2; K = 256; }
  int k = idx >> 8, n = idx & 255;
  float w = W[idx];
  unsigned short hb = f2bf(w);
  float hf = __uint_as_float((unsigned)hb << 16);
  unsigned short lb = f2bf(w - hf);
  hi[(size_t)n * K + k] = hb;
  lo[(size_t)n * K + k] = lb;
}

// ---------------- head-weight pre-split ----------------
// lw0 [64][128] -> bf16 hi/lo transposed [128][64]; lw1 [128][10] -> fp16 T padded [16][128]

__global__ void lwsplit_kernel(const float* __restrict__ lw0,
                               unsigned short* __restrict__ l0hi, unsigned short* __restrict__ l0lo,
                               const float* __restrict__ lw1, _Float16* __restrict__ l1T){
  int idx = blockIdx.x * 256 + threadIdx.x;
  if (idx < 8192){
    int n = idx & 127, k = idx >> 7;     // consecutive lanes -> consecutive n (coalesced read)
    float w = lw0[k * 128 + n];
    unsigned short hb = f2bf(w);
    float hf = __uint_as_float((unsigned)hb << 16);
    unsigned short lb = f2bf(w - hf);
    l0hi[n * 64 + k] = hb;
    l0lo[n * 64 + k] = lb;
  } else if (idx < 8192 + 2048){
    int id = idx - 8192;
    int n = id & 15, k = id >> 4;
    float w = (n < 10) ? lw1[k * 10 + n] : 0.f;
    l1T[n * 128 + k] = (_Float16)w;
  }
}

// ---------------- MFMA GEMM (3x bf16 split), fp16 C output + fused att-score epilogue ----------------
// C[M,256] = A[M,K] @ B[K,256].  128x128 block tile, 4 waves, each 64x64.
// mfma_f32_16x16x32_bf16: A-frag lane: A[m=lane&15][k=(lane>>4)*8+j];
// B-frag lane: B[k=(lane>>4)*8+j][n=lane&15]; C/D: reg r -> row=(lane>>4)*4+r, col=lane&15.

__launch_bounds__(256, 2)
__global__ void gemm_mfma_kernel(const float* __restrict__ A,
                                 const unsigned short* __restrict__ BhiT,
                                 const unsigned short* __restrict__ BloT,
                                 _Float16* __restrict__ Cm,
                                 const float* __restrict__ att_s, const float* __restrict__ att_d,
                                 float* __restrict__ a_src, float* __restrict__ a_dst,
                                 int M, int K){
  __shared__ unsigned short As_hi[128][40];   // stride 40 bf16 = 80B: 16B-aligned, 2-way banks
  __shared__ unsigned short As_lo[128][40];
  __shared__ unsigned short Bs_hi[128][40];   // BT layout: [n][k]
  __shared__ unsigned short Bs_lo[128][40];

  int tid = threadIdx.x;
  int m0 = blockIdx.x * 128, n0 = blockIdx.y * 128;
  int wave = tid >> 6, lane = tid & 63;
  int wm = (wave >> 1) * 64, wn = (wave & 1) * 64;
  int col = lane & 15, quad = lane >> 4;

  f32x4 acc[4][4];
  #pragma unroll
  for (int a = 0; a < 4; a++)
    #pragma unroll
    for (int b = 0; b < 4; b++)
      acc[a][b] = (f32x4){0.f, 0.f, 0.f, 0.f};

  for (int k0 = 0; k0 < K; k0 += 32){
    // stage A (128x32 fp32 -> hi/lo bf16 fragment layout)
    #pragma unroll
    for (int r = 0; r < 2; r++){
      int id = r * 256 + tid;
      int m = id >> 2, q = id & 3;
      int gm = m0 + m;
      float va[8];
      if (gm < M){
        float4 v0 = *(const float4*)&A[(size_t)gm * K + k0 + q * 8];
        float4 v1 = *(const float4*)&A[(size_t)gm * K + k0 + q * 8 + 4];
        va[0]=v0.x; va[1]=v0.y; va[2]=v0.z; va[3]=v0.w;
        va[4]=v1.x; va[5]=v1.y; va[6]=v1.z; va[7]=v1.w;
      } else {
        #pragma unroll
        for (int j = 0; j < 8; j++) va[j] = 0.f;
      }
      short8 hi8, lo8;
      #pragma unroll
      for (int j = 0; j < 8; j++){
        unsigned short hb = f2bf(va[j]);
        float hf = __uint_as_float((unsigned)hb << 16);
        hi8[j] = (short)hb;
        lo8[j] = (short)f2bf(va[j] - hf);
      }
      *(short8*)&As_hi[m][q * 8] = hi8;
      *(short8*)&As_lo[m][q * 8] = lo8;
    }
    // stage B (pre-split bf16, already transposed [n][K])
    #pragma unroll
    for (int r = 0; r < 2; r++){
      int id = r * 256 + tid;
      int n = id >> 2, q = id & 3;
      size_t g = (size_t)(n0 + n) * K + k0 + q * 8;
      *(short8*)&Bs_hi[n][q * 8] = *(const short8*)&BhiT[g];
      *(short8*)&Bs_lo[n][q * 8] = *(const short8*)&BloT[g];
    }
    __syncthreads();

    short8 af[4][2], bf[4][2];
    #pragma unroll
    for (int t = 0; t < 4; t++){
      af[t][0] = *(const short8*)&As_hi[wm + t * 16 + col][quad * 8];
      af[t][1] = *(const short8*)&As_lo[wm + t * 16 + col][quad * 8];
      bf[t][0] = *(const short8*)&Bs_hi[wn + t * 16 + col][quad * 8];
      bf[t][1] = *(const short8*)&Bs_lo[wn + t * 16 + col][quad * 8];
    }
    #pragma unroll
    for (int mt = 0; mt < 4; mt++)
      #pragma unroll
      for (int nt = 0; nt < 4; nt++){
        acc[mt][nt] = __builtin_amdgcn_mfma_f32_16x16x32_bf16(af[mt][0], bf[nt][0], acc[mt][nt], 0, 0, 0);
        acc[mt][nt] = __builtin_amdgcn_mfma_f32_16x16x32_bf16(af[mt][1], bf[nt][0], acc[mt][nt], 0, 0, 0);
        acc[mt][nt] = __builtin_amdgcn_mfma_f32_16x16x32_bf16(af[mt][0], bf[nt][1], acc[mt][nt], 0, 0, 0);
      }
    __syncthreads();
  }

  // store C as fp16
  #pragma unroll
  for (int mt = 0; mt < 4; mt++)
    #pragma unroll
    for (int nt = 0; nt < 4; nt++){
      int colg = n0 + wn + nt * 16 + col;
      #pragma unroll
      for (int r = 0; r < 4; r++){
        int row = m0 + wm + mt * 16 + quad * 4 + r;
        if (row < M) Cm[(size_t)row * HC + colg] = (_Float16)acc[mt][nt][r];
      }
    }

  // fused attention scores; this wave's 64 n-columns == one head
  int head = (n0 + wn) >> 6;
  float asv[4], adv[4];
  #pragma unroll
  for (int nt = 0; nt < 4; nt++){
    asv[nt] = att_s[head * CH + nt * 16 + col];
    adv[nt] = att_d[head * CH + nt * 16 + col];
  }
  #pragma unroll
  for (int mt = 0; mt < 4; mt++){
    float sp[4] = {0.f,0.f,0.f,0.f}, dp[4] = {0.f,0.f,0.f,0.f};
    #pragma unroll
    for (int nt = 0; nt < 4; nt++)
      #pragma unroll
      for (int r = 0; r < 4; r++){
        sp[r] += acc[mt][nt][r] * asv[nt];
        dp[r] += acc[mt][nt][r] * adv[nt];
      }
    #pragma unroll
    for (int off = 1; off <= 8; off <<= 1)
      #pragma unroll
      for (int r = 0; r < 4; r++){
        sp[r] += __shfl_xor(sp[r], off);
        dp[r] += __shfl_xor(dp[r], off);
      }
    if (col == 0){
      #pragma unroll
      for (int r = 0; r < 4; r++){
        int row = m0 + wm + mt * 16 + quad * 4 + r;
        if (row < M){
          a_src[row * HEADS + head] = sp[r];
          a_dst[row * HEADS + head] = dp[r];
        }
      }
    }
  }
}

// ---------------- softmax aggregation: fp16 h gather, single pass, no max ----------------
// block = node; wave = head; lane = eg(3b) x c8(3b): 8 edges in flight, 16B/lane gather.

__global__ void agg_kernel(const _Float16* __restrict__ h, const float* __restrict__ a_src,
                           const float* __restrict__ a_dst, const int* __restrict__ ptr,
                           const int* __restrict__ csr_src, const float* __restrict__ bias,
                           float* __restrict__ out, int N, int mean_mode,
                           const float* __restrict__ b2){
  __shared__ float sm[HEADS][CH];
  int n = blockIdx.x;
  int head = threadIdx.x >> 6;
  int lane = threadIdx.x & 63;
  int eg = lane >> 3, c8 = lane & 7;
  int beg = ptr[n], end = ptr[n + 1];
  float adst = a_dst[n * HEADS + head];

  float acc[8] = {0.f,0.f,0.f,0.f,0.f,0.f,0.f,0.f};
  float ss = 0.f;
  for (int i = beg + eg; i < end; i += 8){
    int s = csr_src[i];
    float e = a_src[s * HEADS + head] + adst;
    e = e > 0.f ? e : 0.2f * e;
    float w = __expf(e);
    half8 hv = *(const half8*)&h[(size_t)s * HC + head * CH + c8 * 8];
    #pragma unroll
    for (int j = 0; j < 8; j++) acc[j] += w * (float)hv[j];
    ss += w;
  }
  #pragma unroll
  for (int off = 8; off <= 32; off <<= 1){
    #pragma unroll
    for (int j = 0; j < 8; j++) acc[j] += __shfl_xor(acc[j], off);
    ss += __shfl_xor(ss, off);
  }
  float inv = 1.f / (ss + 1e-16f);
  #pragma unroll
  for (int j = 0; j < 8; j++) acc[j] *= inv;

  if (!mean_mode){
    if (eg == 0){
      float* op = &out[(size_t)n * HC + head * CH + c8 * 8];
      const float* bp = &bias[head * CH + c8 * 8];
      #pragma unroll
      for (int j = 0; j < 8; j++) op[j] = acc[j] + bp[j];
    }
  } else {
    if (eg == 0){
      #pragma unroll
      for (int j = 0; j < 8; j++) sm[head][c8 * 8 + j] = acc[j];
    }
    __syncthreads();
    int t = threadIdx.x;
    if (t < CH)
      out[(size_t)n * CH + t] =
        0.25f * (sm[0][t] + sm[1][t] + sm[2][t] + sm[3][t]) + b2[t];
  }
}

// ---------------- fused MFMA MLP head ----------------
// Per 64-row block: Z = relu(f2[64,64] @ lw0[64,128] + lb0)  (3x bf16 split, fp32-accurate)
// then out[64,10] = Z @ lw1[128,10] + lb1  (fp16 mfma).

__launch_bounds__(256, 2)
__global__ void head_mfma_kernel(const float* __restrict__ f2,
                                 const unsigned short* __restrict__ lw0hiT,
                                 const unsigned short* __restrict__ lw0loT,
                                 const _Float16* __restrict__ lw1T,
                                 const float* __restrict__ lb0,
                                 const float* __restrict__ lb1,
                                 float* __restrict__ outp, int N){
  // L layout (shorts): As_hi [64][72] @0, As_lo @4608, Bs_hi [128][72] @9216, Bs_lo @18432.
  // Phase 2 reuses L[0..8704) as Zs fp16 [64][136].
  __shared__ __align__(16) unsigned short L[27648];
  __shared__ __align__(16) _Float16 Ls[16][136];
  const int tid = threadIdx.x;
  const int wave = tid >> 6, lane = tid & 63;
  const int col = lane & 15, quad = lane >> 4;
  const int m0 = blockIdx.x * 64;

  // stage lw1T fp16 [16][128]
  { int n = tid >> 4, k = (tid & 15) * 8;
    *(half8*)&Ls[n][k] = *(const half8*)&lw1T[n * 128 + k]; }

  // stage As: f2 64x64 fp32 -> hi/lo split
  #pragma unroll
  for (int r = 0; r < 2; r++){
    int id = r * 256 + tid;
    int m = id >> 3, q = id & 7;
    int gm = m0 + m;
    float va[8];
    if (gm < N){
      float4 v0 = *(const float4*)&f2[(size_t)gm * CH + q * 8];
      float4 v1 = *(const float4*)&f2[(size_t)gm * CH + q * 8 + 4];
      va[0]=v0.x; va[1]=v0.y; va[2]=v0.z; va[3]=v0.w;
      va[4]=v1.x; va[5]=v1.y; va[6]=v1.z; va[7]=v1.w;
    } else {
      #pragma unroll
      for (int j = 0; j < 8; j++) va[j] = 0.f;
    }
    short8 hi8, lo8;
    #pragma unroll
    for (int j = 0; j < 8; j++){
      unsigned short hb = f2bf(va[j]);
      float hf = __uint_as_float((unsigned)hb << 16);
      hi8[j] = (short)hb;
      lo8[j] = (short)f2bf(va[j] - hf);
    }
    *(short8*)&L[m * 72 + q * 8] = hi8;
    *(short8*)&L[4608 + m * 72 + q * 8] = lo8;
  }
  // stage Bs: lw0T hi/lo [128][64]
  #pragma unroll
  for (int r = 0; r < 4; r++){
    int id = r * 256 + tid;
    int n = id >> 3, q = id & 7;
    *(short8*)&L[9216 + n * 72 + q * 8]  = *(const short8*)&lw0hiT[n * 64 + q * 8];
    *(short8*)&L[18432 + n * 72 + q * 8] = *(const short8*)&lw0loT[n * 64 + q * 8];
  }
  __syncthreads();

  // GEMM 1: 64x128, K=64; wave covers all 64 rows x 32 cols (wn = wave*32)
  const int wn = wave * 32;
  f32x4 acc[4][2];
  #pragma unroll
  for (int a = 0; a < 4; a++)
    #pragma unroll
    for (int b = 0; b < 2; b++) acc[a][b] = (f32x4){0.f,0.f,0.f,0.f};

  #pragma unroll
  for (int ks = 0; ks < 2; ks++){
    int k = ks * 32 + quad * 8;
    short8 ah[4], al[4], bh[2], bl[2];
    #pragma unroll
    for (int mt = 0; mt < 4; mt++){
      ah[mt] = *(short8*)&L[(mt * 16 + col) * 72 + k];
      al[mt] = *(short8*)&L[4608 + (mt * 16 + col) * 72 + k];
    }
    #pragma unroll
    for (int nt = 0; nt < 2; nt++){
      bh[nt] = *(short8*)&L[9216 + (wn + nt * 16 + col) * 72 + k];
      bl[nt] = *(short8*)&L[18432 + (wn + nt * 16 + col) * 72 + k];
    }
    #pragma unroll
    for (int mt = 0; mt < 4; mt++)
      #pragma unroll
      for (int nt = 0; nt < 2; nt++){
        acc[mt][nt] = __builtin_amdgcn_mfma_f32_16x16x32_bf16(ah[mt], bh[nt], acc[mt][nt], 0, 0, 0);
        acc[mt][nt] = __builtin_amdgcn_mfma_f32_16x16x32_bf16(al[mt], bh[nt], acc[mt][nt], 0, 0, 0);
        acc[mt][nt] = __builtin_amdgcn_mfma_f32_16x16x32_bf16(ah[mt], bl[nt], acc[mt][nt], 0, 0, 0);
      }
  }
  __syncthreads();

  // epilogue 1: relu(z + lb0) -> Zs fp16 (A-frag layout [m][k])
  _Float16* Zp = (_Float16*)L;
  #pragma unroll
  for (int nt = 0; nt < 2; nt++){
    int n = wn + nt * 16 + col;
    float b = lb0[n];
    #pragma unroll
    for (int mt = 0; mt < 4; mt++)
      #pragma unroll
      for (int r2 = 0; r2 < 4; r2++){
        int m = mt * 16 + quad * 4 + r2;
        float z = acc[mt][nt][r2] + b;
        Zp[m * 136 + n] = (_Float16)fmaxf(z, 0.f);
      }
  }
  __syncthreads();

  // GEMM 2: 16 rows per wave x 16 cols (10 used), K=128, fp16 mfma
  f32x4 acc2 = (f32x4){0.f,0.f,0.f,0.f};
  #pragma unroll
  for (int ks = 0; ks < 4; ks++){
    int k = ks * 32 + quad * 8;
    half8 a2 = *(half8*)&Zp[(wave * 16 + col) * 136 + k];
    half8 b2v = *(half8*)&Ls[col][k];
    acc2 = __builtin_amdgcn_mfma_f32_16x16x32_f16(a2, b2v, acc2, 0, 0, 0);
  }
  if (col < 10){
    float bb = lb1[col];
    #pragma unroll
    for (int r2 = 0; r2 < 4; r2++){
      int row = m0 + wave * 16 + quad * 4 + r2;
      if (row < N) outp[(size_t)row * 10 + col] = acc2[r2] + bb;
    }
  }
}

// ---------------- launcher ----------------

extern "C" void kernel_launch(void* const* d_in, const int* in_sizes, int n_in,
                              void* d_out, int out_size, void* d_ws, size_t ws_size,
                              hipStream_t stream) {
  const float* x   = (const float*)d_in[0];
  const int*   ei  = (const int*)d_in[1];
  const float* W0  = (const float*)d_in[2];
  const float* as0 = (const float*)d_in[3];
  const float* ad0 = (const float*)d_in[4];
  const float* b0  = (const float*)d_in[5];
  const float* W1  = (const float*)d_in[6];
  const float* as1 = (const float*)d_in[7];
  const float* ad1 = (const float*)d_in[8];
  const float* b1  = (const float*)d_in[9];
  const float* W2  = (const float*)d_in[10];
  const float* as2 = (const float*)d_in[11];
  const float* ad2 = (const float*)d_in[12];
  const float* b2  = (const float*)d_in[13];
  const float* lw0 = (const float*)d_in[14];
  const float* lb0 = (const float*)d_in[15];
  const float* lw1 = (const float*)d_in[16];
  const float* lb1 = (const float*)d_in[17];
  float* outp = (float*)d_out;

  int N  = in_sizes[0] / 128;
  int E  = in_sizes[1] / 2;
  int ET = E + N;
  int nb = (N + 255) / 256;

  char* ws = (char*)d_ws;
  float* F       = (float*)ws;    ws += (size_t)N * HC * sizeof(float);
  _Float16* Hb   = (_Float16*)ws; ws += (size_t)N * HC * sizeof(_Float16);
  float* a_s = (float*)ws; ws += (size_t)N * HEADS * sizeof(float);
  float* a_d = (float*)ws; ws += (size_t)N * HEADS * sizeof(float);
  int* cnt   = (int*)ws;   ws += (size_t)N * sizeof(int);
  int* cur   = (int*)ws;   ws += (size_t)N * sizeof(int);
  int* ptrA  = (int*)ws;   ws += (size_t)(N + 1) * sizeof(int);
  int* bsum  = (int*)ws;   ws += (size_t)nb * sizeof(int);
  int* csr   = (int*)ws;   ws += (size_t)ET * sizeof(int);
  unsigned short* w0hi = (unsigned short*)ws; ws += (size_t)128 * HC * 2;
  unsigned short* w0lo = (unsigned short*)ws; ws += (size_t)128 * HC * 2;
  unsigned short* w1hi = (unsigned short*)ws; ws += (size_t)HC * HC * 2;
  unsigned short* w1lo = (unsigned short*)ws; ws += (size_t)HC * HC * 2;
  unsigned short* w2hi = (unsigned short*)ws; ws += (size_t)HC * HC * 2;
  unsigned short* w2lo = (unsigned short*)ws; ws += (size_t)HC * HC * 2;
  unsigned short* l0hi = (unsigned short*)ws; ws += (size_t)8192 * 2;
  unsigned short* l0lo = (unsigned short*)ws; ws += (size_t)8192 * 2;
  _Float16* l1T        = (_Float16*)ws;       ws += (size_t)2048 * 2;
  float* f2  = F;   // layer-2 mean output reuses F (Hb holds h, still live during agg)

  const int* srcArr = ei;
  const int* dstArr = ei + E;

  // CSR build
  hipMemsetAsync(cnt, 0, (size_t)N * sizeof(int), stream);
  hist_kernel<<<(ET + 255) / 256, 256, 0, stream>>>(dstArr, E, ET, cnt);
  blocksum_kernel<<<nb, 256, 0, stream>>>(cnt, N, bsum);
  scanb_kernel<<<1, 256, 0, stream>>>(bsum, nb);
  scanfinal_kernel<<<nb, 256, 0, stream>>>(cnt, bsum, ptrA, cur, N);
  scatter_kernel<<<(ET + 255) / 256, 256, 0, stream>>>(srcArr, dstArr, E, ET, cur, csr);

  // weight pre-splits
  wsplit_kernel<<<((128 + 256 + 256) * HC) / 256, 256, 0, stream>>>(
      W0, w0hi, w0lo, W1, w1hi, w1lo, W2, w2hi, w2lo);
  lwsplit_kernel<<<(8192 + 2048 + 255) / 256, 256, 0, stream>>>(lw0, l0hi, l0lo, lw1, l1T);

  dim3 ggrid((N + 127) / 128, 2);

  // layer 0: 128 -> 4x64, concat
  gemm_mfma_kernel<<<ggrid, 256, 0, stream>>>(x, w0hi, w0lo, Hb, as0, ad0, a_s, a_d, N, 128);
  agg_kernel<<<N, 256, 0, stream>>>(Hb, a_s, a_d, ptrA, csr, b0, F, N, 0, nullptr);

  // layer 1: 256 -> 4x64, concat
  gemm_mfma_kernel<<<ggrid, 256, 0, stream>>>(F, w1hi, w1lo, Hb, as1, ad1, a_s, a_d, N, HC);
  agg_kernel<<<N, 256, 0, stream>>>(Hb, a_s, a_d, ptrA, csr, b1, F, N, 0, nullptr);

  // layer 2: 256 -> 4x64, mean over heads (+b2)
  gemm_mfma_kernel<<<ggrid, 256, 0, stream>>>(F, w2hi, w2lo, Hb, as2, ad2, a_s, a_d, N, HC);
  agg_kernel<<<N, 256, 0, stream>>>(Hb, a_s, a_d, ptrA, csr, nullptr, f2, N, 1, b2);

  // MFMA MLP head
  head_mfma_kernel<<<(N + 63) / 64, 256, 0, stream>>>(f2, l0hi, l0lo, l1T, lb0, lb1, outp, N);
}

// Round 6
// 593.820 us; speedup vs baseline: 2.2555x; 1.0033x over previous
//
#include <hip/hip_runtime.h>
#include <hip/hip_bf16.h>

#define HEADS 4
#define CH 64
#define HC 256

typedef __attribute__((ext_vector_type(8))) short short8;
typedef __attribute__((ext_vector_type(4))) float f32x4;
typedef __attribute__((ext_vector_type(8))) _Float16 half8;

__device__ inline unsigned short f2bf(float f){
  unsigned u = __float_as_uint(f);
  return (unsigned short)((u + 0x7FFF + ((u >> 16) & 1)) >> 16);
}

// ---------------- CSR build ----------------

__global__ void hist_kernel(const int* __restrict__ dst, int E, int ET, int* __restrict__ cnt){
  int e = blockIdx.x * blockDim.x + threadIdx.x;
  if (e >= ET) return;
  int d = (e < E) ? dst[e] : (e - E);   // self-loop edges appended
  atomicAdd(&cnt[d], 1);
}

__global__ void blocksum_kernel(const int* __restrict__ cnt, int N, int* __restrict__ bsum){
  int tid = threadIdx.x;
  int i = blockIdx.x * 256 + tid;
  int v = (i < N) ? cnt[i] : 0;
  #pragma unroll
  for (int off = 32; off >= 1; off >>= 1) v += __shfl_xor(v, off);
  __shared__ int ws[4];
  if ((tid & 63) == 0) ws[tid >> 6] = v;
  __syncthreads();
  if (tid == 0) bsum[blockIdx.x] = ws[0] + ws[1] + ws[2] + ws[3];
}

__global__ void scanb_kernel(int* __restrict__ bsum, int nb){
  __shared__ int buf[256];
  int tid = threadIdx.x;
  int v = (tid < nb) ? bsum[tid] : 0;
  buf[tid] = v;
  __syncthreads();
  #pragma unroll
  for (int off = 1; off < 256; off <<= 1){
    int t = (tid >= off) ? buf[tid - off] : 0;
    __syncthreads();
    buf[tid] += t;
    __syncthreads();
  }
  if (tid < nb) bsum[tid] = buf[tid] - v;  // exclusive
}

__global__ void scanfinal_kernel(const int* __restrict__ cnt, const int* __restrict__ bsum,
                                 int* __restrict__ ptr, int* __restrict__ cur, int N){
  __shared__ int buf[256];
  int tid = threadIdx.x;
  int i = blockIdx.x * 256 + tid;
  int v = (i < N) ? cnt[i] : 0;
  buf[tid] = v;
  __syncthreads();
  #pragma unroll
  for (int off = 1; off < 256; off <<= 1){
    int t = (tid >= off) ? buf[tid - off] : 0;
    __syncthreads();
    buf[tid] += t;
    __syncthreads();
  }
  int exc = buf[tid] - v + bsum[blockIdx.x];
  if (i < N){
    ptr[i] = exc; cur[i] = exc;
    if (i == N - 1) ptr[N] = exc + v;
  }
}

__global__ void scatter_kernel(const int* __restrict__ src, const int* __restrict__ dst,
                               int E, int ET, int* __restrict__ cur, int* __restrict__ csr_src){
  int e = blockIdx.x * blockDim.x + threadIdx.x;
  if (e >= ET) return;
  int s, d;
  if (e < E){ s = src[e]; d = dst[e]; } else { s = e - E; d = e - E; }
  int pos = atomicAdd(&cur[d], 1);
  csr_src[pos] = s;
}

// ---------------- W pre-split (all 3 layers in one launch) ----------------
// fp32 [K][256] -> bf16 hi/lo transposed [256][K]

__global__ void wsplit_kernel(const float* __restrict__ W0, unsigned short* __restrict__ h0,
                              unsigned short* __restrict__ l0,
                              const float* __restrict__ W1, unsigned short* __restrict__ h1,
                              unsigned short* __restrict__ l1,
                              const float* __restrict__ W2, unsigned short* __restrict__ h2,
                              unsigned short* __restrict__ l2){
  int idx = blockIdx.x * 256 + threadIdx.x;
  const float* W; unsigned short *hi, *lo; int K;
  if (idx < 128 * HC){ W = W0; hi = h0; lo = l0; K = 128; }
  else if (idx < (128 + 256) * HC){ idx -= 128 * HC; W = W1; hi = h1; lo = l1; K = 256; }
  else { idx -= (128 + 256) * HC; W = W2; hi = h2; lo = l2; K = 256; }
  int k = idx >> 8, n = idx & 255;
  float w = W[idx];
  unsigned short hb = f2bf(w);
  float hf = __uint_as_float((unsigned)hb << 16);
  unsigned short lb = f2bf(w - hf);
  hi[(size_t)n * K + k] = hb;
  lo[(size_t)n * K + k] = lb;
}

// ---------------- x pre-split: fp32 [N][128] -> hi/lo bf16 row-major ----------------

__global__ void xsplit_kernel(const float* __restrict__ x, int total4,
                              unsigned short* __restrict__ xhi, unsigned short* __restrict__ xlo){
  int i4 = blockIdx.x * 256 + threadIdx.x;
  if (i4 >= total4) return;
  float4 v = *(const float4*)&x[(size_t)i4 * 4];
  float va[4] = {v.x, v.y, v.z, v.w};
  unsigned short h4[4], l4[4];
  #pragma unroll
  for (int j = 0; j < 4; j++){
    unsigned short hb = f2bf(va[j]);
    float hf = __uint_as_float((unsigned)hb << 16);
    h4[j] = hb;
    l4[j] = f2bf(va[j] - hf);
  }
  *(ushort4*)&xhi[(size_t)i4 * 4] = make_ushort4(h4[0], h4[1], h4[2], h4[3]);
  *(ushort4*)&xlo[(size_t)i4 * 4] = make_ushort4(l4[0], l4[1], l4[2], l4[3]);
}

// ---------------- head-weight pre-split ----------------
// lw0 [64][128] -> bf16 hi/lo transposed [128][64]; lw1 [128][10] -> fp16 T padded [16][128]

__global__ void lwsplit_kernel(const float* __restrict__ lw0,
                               unsigned short* __restrict__ l0hi, unsigned short* __restrict__ l0lo,
                               const float* __restrict__ lw1, _Float16* __restrict__ l1T){
  int idx = blockIdx.x * 256 + threadIdx.x;
  if (idx < 8192){
    int n = idx & 127, k = idx >> 7;     // consecutive lanes -> consecutive n (coalesced read)
    float w = lw0[k * 128 + n];
    unsigned short hb = f2bf(w);
    float hf = __uint_as_float((unsigned)hb << 16);
    unsigned short lb = f2bf(w - hf);
    l0hi[n * 64 + k] = hb;
    l0lo[n * 64 + k] = lb;
  } else if (idx < 8192 + 2048){
    int id = idx - 8192;
    int n = id & 15, k = id >> 4;
    float w = (n < 10) ? lw1[k * 10 + n] : 0.f;
    l1T[n * 128 + k] = (_Float16)w;
  }
}

// ---------------- MFMA GEMM (3x bf16 split), pre-split A, fp16 C + fused att-score epilogue ----
// C[M,256] = A[M,K] @ B[K,256].  A given as hi/lo bf16 [M][K]; B as hi/lo bf16 T [256][K].
// 128x128 block tile, 4 waves, each 64x64.
// mfma_f32_16x16x32_bf16: A-frag lane: A[m=lane&15][k=(lane>>4)*8+j];
// B-frag lane: B[k=(lane>>4)*8+j][n=lane&15]; C/D: reg r -> row=(lane>>4)*4+r, col=lane&15.

__launch_bounds__(256, 2)
__global__ void gemm_mfma_kernel(const unsigned short* __restrict__ Ahi,
                                 const unsigned short* __restrict__ Alo,
                                 const unsigned short* __restrict__ BhiT,
                                 const unsigned short* __restrict__ BloT,
                                 _Float16* __restrict__ Cm,
                                 const float* __restrict__ att_s, const float* __restrict__ att_d,
                                 float* __restrict__ a_src, float* __restrict__ a_dst,
                                 int M, int K){
  __shared__ unsigned short As_hi[128][40];   // stride 40 bf16 = 80B: 16B-aligned, 2-way banks
  __shared__ unsigned short As_lo[128][40];
  __shared__ unsigned short Bs_hi[128][40];   // BT layout: [n][k]
  __shared__ unsigned short Bs_lo[128][40];

  int tid = threadIdx.x;
  int m0 = blockIdx.x * 128, n0 = blockIdx.y * 128;
  int wave = tid >> 6, lane = tid & 63;
  int wm = (wave >> 1) * 64, wn = (wave & 1) * 64;
  int col = lane & 15, quad = lane >> 4;

  f32x4 acc[4][4];
  #pragma unroll
  for (int a = 0; a < 4; a++)
    #pragma unroll
    for (int b = 0; b < 4; b++)
      acc[a][b] = (f32x4){0.f, 0.f, 0.f, 0.f};

  const short8 zero8 = (short8){0,0,0,0,0,0,0,0};

  for (int k0 = 0; k0 < K; k0 += 32){
    // stage A (pre-split hi/lo, pure copy)
    #pragma unroll
    for (int r = 0; r < 2; r++){
      int id = r * 256 + tid;
      int m = id >> 2, q = id & 3;
      int gm = m0 + m;
      size_t g = (size_t)gm * K + k0 + q * 8;
      short8 vh = zero8, vl = zero8;
      if (gm < M){
        vh = *(const short8*)&Ahi[g];
        vl = *(const short8*)&Alo[g];
      }
      *(short8*)&As_hi[m][q * 8] = vh;
      *(short8*)&As_lo[m][q * 8] = vl;
    }
    // stage B (pre-split bf16, already transposed [n][K])
    #pragma unroll
    for (int r = 0; r < 2; r++){
      int id = r * 256 + tid;
      int n = id >> 2, q = id & 3;
      size_t g = (size_t)(n0 + n) * K + k0 + q * 8;
      *(short8*)&Bs_hi[n][q * 8] = *(const short8*)&BhiT[g];
      *(short8*)&Bs_lo[n][q * 8] = *(const short8*)&BloT[g];
    }
    __syncthreads();

    short8 af[4][2], bf[4][2];
    #pragma unroll
    for (int t = 0; t < 4; t++){
      af[t][0] = *(const short8*)&As_hi[wm + t * 16 + col][quad * 8];
      af[t][1] = *(const short8*)&As_lo[wm + t * 16 + col][quad * 8];
      bf[t][0] = *(const short8*)&Bs_hi[wn + t * 16 + col][quad * 8];
      bf[t][1] = *(const short8*)&Bs_lo[wn + t * 16 + col][quad * 8];
    }
    #pragma unroll
    for (int mt = 0; mt < 4; mt++)
      #pragma unroll
      for (int nt = 0; nt < 4; nt++){
        acc[mt][nt] = __builtin_amdgcn_mfma_f32_16x16x32_bf16(af[mt][0], bf[nt][0], acc[mt][nt], 0, 0, 0);
        acc[mt][nt] = __builtin_amdgcn_mfma_f32_16x16x32_bf16(af[mt][1], bf[nt][0], acc[mt][nt], 0, 0, 0);
        acc[mt][nt] = __builtin_amdgcn_mfma_f32_16x16x32_bf16(af[mt][0], bf[nt][1], acc[mt][nt], 0, 0, 0);
      }
    __syncthreads();
  }

  // store C as fp16
  #pragma unroll
  for (int mt = 0; mt < 4; mt++)
    #pragma unroll
    for (int nt = 0; nt < 4; nt++){
      int colg = n0 + wn + nt * 16 + col;
      #pragma unroll
      for (int r = 0; r < 4; r++){
        int row = m0 + wm + mt * 16 + quad * 4 + r;
        if (row < M) Cm[(size_t)row * HC + colg] = (_Float16)acc[mt][nt][r];
      }
    }

  // fused attention scores; this wave's 64 n-columns == one head
  int head = (n0 + wn) >> 6;
  float asv[4], adv[4];
  #pragma unroll
  for (int nt = 0; nt < 4; nt++){
    asv[nt] = att_s[head * CH + nt * 16 + col];
    adv[nt] = att_d[head * CH + nt * 16 + col];
  }
  #pragma unroll
  for (int mt = 0; mt < 4; mt++){
    float sp[4] = {0.f,0.f,0.f,0.f}, dp[4] = {0.f,0.f,0.f,0.f};
    #pragma unroll
    for (int nt = 0; nt < 4; nt++)
      #pragma unroll
      for (int r = 0; r < 4; r++){
        sp[r] += acc[mt][nt][r] * asv[nt];
        dp[r] += acc[mt][nt][r] * adv[nt];
      }
    #pragma unroll
    for (int off = 1; off <= 8; off <<= 1)
      #pragma unroll
      for (int r = 0; r < 4; r++){
        sp[r] += __shfl_xor(sp[r], off);
        dp[r] += __shfl_xor(dp[r], off);
      }
    if (col == 0){
      #pragma unroll
      for (int r = 0; r < 4; r++){
        int row = m0 + wm + mt * 16 + quad * 4 + r;
        if (row < M){
          a_src[row * HEADS + head] = sp[r];
          a_dst[row * HEADS + head] = dp[r];
        }
      }
    }
  }
}

// ---------------- softmax aggregation: fp16 gather, 2 streams (16 edges in flight) ----------------
// block = node; wave = head; lane = eg(3b) x c8(3b).
// concat mode: writes hi/lo bf16 split (next GEMM's A); mean mode: writes fp32 f2.

__global__ void agg_kernel(const _Float16* __restrict__ h, const float* __restrict__ a_src,
                           const float* __restrict__ a_dst, const int* __restrict__ ptr,
                           const int* __restrict__ csr_src, const float* __restrict__ bias,
                           unsigned short* __restrict__ out_hi, unsigned short* __restrict__ out_lo,
                           int N, int mean_mode, const float* __restrict__ b2,
                           float* __restrict__ f2){
  __shared__ float sm[HEADS][CH];
  int n = blockIdx.x;
  int head = threadIdx.x >> 6;
  int lane = threadIdx.x & 63;
  int eg = lane >> 3, c8 = lane & 7;
  int beg = ptr[n], end = ptr[n + 1];
  float adst = a_dst[n * HEADS + head];

  float acc0[8] = {0.f,0.f,0.f,0.f,0.f,0.f,0.f,0.f};
  float acc1[8] = {0.f,0.f,0.f,0.f,0.f,0.f,0.f,0.f};
  float ss0 = 0.f, ss1 = 0.f;
  int i = beg + eg;
  for (; i + 8 < end; i += 16){
    int s0 = csr_src[i], s1 = csr_src[i + 8];
    float e0 = a_src[s0 * HEADS + head] + adst;
    float e1 = a_src[s1 * HEADS + head] + adst;
    e0 = e0 > 0.f ? e0 : 0.2f * e0;
    e1 = e1 > 0.f ? e1 : 0.2f * e1;
    float w0 = __expf(e0), w1 = __expf(e1);
    half8 h0 = *(const half8*)&h[(size_t)s0 * HC + head * CH + c8 * 8];
    half8 h1 = *(const half8*)&h[(size_t)s1 * HC + head * CH + c8 * 8];
    #pragma unroll
    for (int j = 0; j < 8; j++){
      acc0[j] += w0 * (float)h0[j];
      acc1[j] += w1 * (float)h1[j];
    }
    ss0 += w0; ss1 += w1;
  }
  if (i < end){
    int s0 = csr_src[i];
    float e0 = a_src[s0 * HEADS + head] + adst;
    e0 = e0 > 0.f ? e0 : 0.2f * e0;
    float w0 = __expf(e0);
    half8 h0 = *(const half8*)&h[(size_t)s0 * HC + head * CH + c8 * 8];
    #pragma unroll
    for (int j = 0; j < 8; j++) acc0[j] += w0 * (float)h0[j];
    ss0 += w0;
  }
  float ss = ss0 + ss1;
  float acc[8];
  #pragma unroll
  for (int j = 0; j < 8; j++) acc[j] = acc0[j] + acc1[j];
  #pragma unroll
  for (int off = 8; off <= 32; off <<= 1){
    #pragma unroll
    for (int j = 0; j < 8; j++) acc[j] += __shfl_xor(acc[j], off);
    ss += __shfl_xor(ss, off);
  }
  float inv = 1.f / (ss + 1e-16f);
  #pragma unroll
  for (int j = 0; j < 8; j++) acc[j] *= inv;

  if (!mean_mode){
    if (eg == 0){
      const float* bp = &bias[head * CH + c8 * 8];
      short8 hi8, lo8;
      #pragma unroll
      for (int j = 0; j < 8; j++){
        float v = acc[j] + bp[j];
        unsigned short hb = f2bf(v);
        float hf = __uint_as_float((unsigned)hb << 16);
        hi8[j] = (short)hb;
        lo8[j] = (short)f2bf(v - hf);
      }
      size_t o = (size_t)n * HC + head * CH + c8 * 8;
      *(short8*)&out_hi[o] = hi8;
      *(short8*)&out_lo[o] = lo8;
    }
  } else {
    if (eg == 0){
      #pragma unroll
      for (int j = 0; j < 8; j++) sm[head][c8 * 8 + j] = acc[j];
    }
    __syncthreads();
    int t = threadIdx.x;
    if (t < CH)
      f2[(size_t)n * CH + t] =
        0.25f * (sm[0][t] + sm[1][t] + sm[2][t] + sm[3][t]) + b2[t];
  }
}

// ---------------- fused MFMA MLP head ----------------
// Per 64-row block: Z = relu(f2[64,64] @ lw0[64,128] + lb0)  (3x bf16 split, fp32-accurate)
// then out[64,10] = Z @ lw1[128,10] + lb1  (fp16 mfma).

__launch_bounds__(256, 2)
__global__ void head_mfma_kernel(const float* __restrict__ f2,
                                 const unsigned short* __restrict__ lw0hiT,
                                 const unsigned short* __restrict__ lw0loT,
                                 const _Float16* __restrict__ lw1T,
                                 const float* __restrict__ lb0,
                                 const float* __restrict__ lb1,
                                 float* __restrict__ outp, int N){
  // L layout (shorts): As_hi [64][72] @0, As_lo @4608, Bs_hi [128][72] @9216, Bs_lo @18432.
  // Phase 2 reuses L[0..8704) as Zs fp16 [64][136].
  __shared__ __align__(16) unsigned short L[27648];
  __shared__ __align__(16) _Float16 Ls[16][136];
  const int tid = threadIdx.x;
  const int wave = tid >> 6, lane = tid & 63;
  const int col = lane & 15, quad = lane >> 4;
  const int m0 = blockIdx.x * 64;

  // stage lw1T fp16 [16][128]
  { int n = tid >> 4, k = (tid & 15) * 8;
    *(half8*)&Ls[n][k] = *(const half8*)&lw1T[n * 128 + k]; }

  // stage As: f2 64x64 fp32 -> hi/lo split
  #pragma unroll
  for (int r = 0; r < 2; r++){
    int id = r * 256 + tid;
    int m = id >> 3, q = id & 7;
    int gm = m0 + m;
    float va[8];
    if (gm < N){
      float4 v0 = *(const float4*)&f2[(size_t)gm * CH + q * 8];
      float4 v1 = *(const float4*)&f2[(size_t)gm * CH + q * 8 + 4];
      va[0]=v0.x; va[1]=v0.y; va[2]=v0.z; va[3]=v0.w;
      va[4]=v1.x; va[5]=v1.y; va[6]=v1.z; va[7]=v1.w;
    } else {
      #pragma unroll
      for (int j = 0; j < 8; j++) va[j] = 0.f;
    }
    short8 hi8, lo8;
    #pragma unroll
    for (int j = 0; j < 8; j++){
      unsigned short hb = f2bf(va[j]);
      float hf = __uint_as_float((unsigned)hb << 16);
      hi8[j] = (short)hb;
      lo8[j] = (short)f2bf(va[j] - hf);
    }
    *(short8*)&L[m * 72 + q * 8] = hi8;
    *(short8*)&L[4608 + m * 72 + q * 8] = lo8;
  }
  // stage Bs: lw0T hi/lo [128][64]
  #pragma unroll
  for (int r = 0; r < 4; r++){
    int id = r * 256 + tid;
    int n = id >> 3, q = id & 7;
    *(short8*)&L[9216 + n * 72 + q * 8]  = *(const short8*)&lw0hiT[n * 64 + q * 8];
    *(short8*)&L[18432 + n * 72 + q * 8] = *(const short8*)&lw0loT[n * 64 + q * 8];
  }
  __syncthreads();

  // GEMM 1: 64x128, K=64; wave covers all 64 rows x 32 cols (wn = wave*32)
  const int wn = wave * 32;
  f32x4 acc[4][2];
  #pragma unroll
  for (int a = 0; a < 4; a++)
    #pragma unroll
    for (int b = 0; b < 2; b++) acc[a][b] = (f32x4){0.f,0.f,0.f,0.f};

  #pragma unroll
  for (int ks = 0; ks < 2; ks++){
    int k = ks * 32 + quad * 8;
    short8 ah[4], al[4], bh[2], bl[2];
    #pragma unroll
    for (int mt = 0; mt < 4; mt++){
      ah[mt] = *(short8*)&L[(mt * 16 + col) * 72 + k];
      al[mt] = *(short8*)&L[4608 + (mt * 16 + col) * 72 + k];
    }
    #pragma unroll
    for (int nt = 0; nt < 2; nt++){
      bh[nt] = *(short8*)&L[9216 + (wn + nt * 16 + col) * 72 + k];
      bl[nt] = *(short8*)&L[18432 + (wn + nt * 16 + col) * 72 + k];
    }
    #pragma unroll
    for (int mt = 0; mt < 4; mt++)
      #pragma unroll
      for (int nt = 0; nt < 2; nt++){
        acc[mt][nt] = __builtin_amdgcn_mfma_f32_16x16x32_bf16(ah[mt], bh[nt], acc[mt][nt], 0, 0, 0);
        acc[mt][nt] = __builtin_amdgcn_mfma_f32_16x16x32_bf16(al[mt], bh[nt], acc[mt][nt], 0, 0, 0);
        acc[mt][nt] = __builtin_amdgcn_mfma_f32_16x16x32_bf16(ah[mt], bl[nt], acc[mt][nt], 0, 0, 0);
      }
  }
  __syncthreads();

  // epilogue 1: relu(z + lb0) -> Zs fp16 (A-frag layout [m][k])
  _Float16* Zp = (_Float16*)L;
  #pragma unroll
  for (int nt = 0; nt < 2; nt++){
    int n = wn + nt * 16 + col;
    float b = lb0[n];
    #pragma unroll
    for (int mt = 0; mt < 4; mt++)
      #pragma unroll
      for (int r2 = 0; r2 < 4; r2++){
        int m = mt * 16 + quad * 4 + r2;
        float z = acc[mt][nt][r2] + b;
        Zp[m * 136 + n] = (_Float16)fmaxf(z, 0.f);
      }
  }
  __syncthreads();

  // GEMM 2: 16 rows per wave x 16 cols (10 used), K=128, fp16 mfma
  f32x4 acc2 = (f32x4){0.f,0.f,0.f,0.f};
  #pragma unroll
  for (int ks = 0; ks < 4; ks++){
    int k = ks * 32 + quad * 8;
    half8 a2 = *(half8*)&Zp[(wave * 16 + col) * 136 + k];
    half8 b2v = *(half8*)&Ls[col][k];
    acc2 = __builtin_amdgcn_mfma_f32_16x16x32_f16(a2, b2v, acc2, 0, 0, 0);
  }
  if (col < 10){
    float bb = lb1[col];
    #pragma unroll
    for (int r2 = 0; r2 < 4; r2++){
      int row = m0 + wave * 16 + quad * 4 + r2;
      if (row < N) outp[(size_t)row * 10 + col] = acc2[r2] + bb;
    }
  }
}

// ---------------- launcher ----------------

extern "C" void kernel_launch(void* const* d_in, const int* in_sizes, int n_in,
                              void* d_out, int out_size, void* d_ws, size_t ws_size,
                              hipStream_t stream) {
  const float* x   = (const float*)d_in[0];
  const int*   ei  = (const int*)d_in[1];
  const float* W0  = (const float*)d_in[2];
  const float* as0 = (const float*)d_in[3];
  const float* ad0 = (const float*)d_in[4];
  const float* b0  = (const float*)d_in[5];
  const float* W1  = (const float*)d_in[6];
  const float* as1 = (const float*)d_in[7];
  const float* ad1 = (const float*)d_in[8];
  const float* b1  = (const float*)d_in[9];
  const float* W2  = (const float*)d_in[10];
  const float* as2 = (const float*)d_in[11];
  const float* ad2 = (const float*)d_in[12];
  const float* b2  = (const float*)d_in[13];
  const float* lw0 = (const float*)d_in[14];
  const float* lb0 = (const float*)d_in[15];
  const float* lw1 = (const float*)d_in[16];
  const float* lb1 = (const float*)d_in[17];
  float* outp = (float*)d_out;

  int N  = in_sizes[0] / 128;
  int E  = in_sizes[1] / 2;
  int ET = E + N;
  int nb = (N + 255) / 256;

  char* ws = (char*)d_ws;
  _Float16* Hb = (_Float16*)ws;       ws += (size_t)N * HC * sizeof(_Float16);
  unsigned short* Fhi = (unsigned short*)ws; ws += (size_t)N * HC * 2;  // also holds xhi (N x 128)
  unsigned short* Flo = (unsigned short*)ws; ws += (size_t)N * HC * 2;  // also holds xlo
  float* f2  = (float*)ws; ws += (size_t)N * CH * sizeof(float);
  float* a_s = (float*)ws; ws += (size_t)N * HEADS * sizeof(float);
  float* a_d = (float*)ws; ws += (size_t)N * HEADS * sizeof(float);
  int* cnt   = (int*)ws;   ws += (size_t)N * sizeof(int);
  int* cur   = (int*)ws;   ws += (size_t)N * sizeof(int);
  int* ptrA  = (int*)ws;   ws += (size_t)(N + 1) * sizeof(int);
  int* bsum  = (int*)ws;   ws += (size_t)nb * sizeof(int);
  int* csr   = (int*)ws;   ws += (size_t)ET * sizeof(int);
  unsigned short* w0hi = (unsigned short*)ws; ws += (size_t)128 * HC * 2;
  unsigned short* w0lo = (unsigned short*)ws; ws += (size_t)128 * HC * 2;
  unsigned short* w1hi = (unsigned short*)ws; ws += (size_t)HC * HC * 2;
  unsigned short* w1lo = (unsigned short*)ws; ws += (size_t)HC * HC * 2;
  unsigned short* w2hi = (unsigned short*)ws; ws += (size_t)HC * HC * 2;
  unsigned short* w2lo = (unsigned short*)ws; ws += (size_t)HC * HC * 2;
  unsigned short* l0hi = (unsigned short*)ws; ws += (size_t)8192 * 2;
  unsigned short* l0lo = (unsigned short*)ws; ws += (size_t)8192 * 2;
  _Float16* l1T        = (_Float16*)ws;       ws += (size_t)2048 * 2;

  const int* srcArr = ei;
  const int* dstArr = ei + E;

  // CSR build
  hipMemsetAsync(cnt, 0, (size_t)N * sizeof(int), stream);
  hist_kernel<<<(ET + 255) / 256, 256, 0, stream>>>(dstArr, E, ET, cnt);
  blocksum_kernel<<<nb, 256, 0, stream>>>(cnt, N, bsum);
  scanb_kernel<<<1, 256, 0, stream>>>(bsum, nb);
  scanfinal_kernel<<<nb, 256, 0, stream>>>(cnt, bsum, ptrA, cur, N);
  scatter_kernel<<<(ET + 255) / 256, 256, 0, stream>>>(srcArr, dstArr, E, ET, cur, csr);

  // weight pre-splits + x pre-split (x split lives in Fhi/Flo until agg layer-0 overwrites)
  wsplit_kernel<<<((128 + 256 + 256) * HC) / 256, 256, 0, stream>>>(
      W0, w0hi, w0lo, W1, w1hi, w1lo, W2, w2hi, w2lo);
  lwsplit_kernel<<<(8192 + 2048 + 255) / 256, 256, 0, stream>>>(lw0, l0hi, l0lo, lw1, l1T);
  xsplit_kernel<<<(N * 128 / 4 + 255) / 256, 256, 0, stream>>>(x, N * 128 / 4, Fhi, Flo);

  dim3 ggrid((N + 127) / 128, 2);

  // layer 0: 128 -> 4x64, concat  (A = pre-split x in Fhi/Flo)
  gemm_mfma_kernel<<<ggrid, 256, 0, stream>>>(Fhi, Flo, w0hi, w0lo, Hb, as0, ad0, a_s, a_d, N, 128);
  agg_kernel<<<N, 256, 0, stream>>>(Hb, a_s, a_d, ptrA, csr, b0, Fhi, Flo, N, 0, nullptr, nullptr);

  // layer 1: 256 -> 4x64, concat
  gemm_mfma_kernel<<<ggrid, 256, 0, stream>>>(Fhi, Flo, w1hi, w1lo, Hb, as1, ad1, a_s, a_d, N, HC);
  agg_kernel<<<N, 256, 0, stream>>>(Hb, a_s, a_d, ptrA, csr, b1, Fhi, Flo, N, 0, nullptr, nullptr);

  // layer 2: 256 -> 4x64, mean over heads (+b2) -> f2 fp32
  gemm_mfma_kernel<<<ggrid, 256, 0, stream>>>(Fhi, Flo, w2hi, w2lo, Hb, as2, ad2, a_s, a_d, N, HC);
  agg_kernel<<<N, 256, 0, stream>>>(Hb, a_s, a_d, ptrA, csr, nullptr, nullptr, nullptr, N, 1, b2, f2);

  // MFMA MLP head
  head_mfma_kernel<<<(N + 63) / 64, 256, 0, stream>>>(f2, l0hi, l0lo, l1T, lb0, lb1, outp, N);
}

// Round 7
// 587.856 us; speedup vs baseline: 2.2783x; 1.0101x over previous
//
#include <hip/hip_runtime.h>
#include <hip/hip_bf16.h>

#define HEADS 4
#define CH 64
#define HC 256

typedef __attribute__((ext_vector_type(8))) short short8;
typedef __attribute__((ext_vector_type(4))) float f32x4;
typedef __attribute__((ext_vector_type(8))) _Float16 half8;

__device__ inline unsigned short f2bf(float f){
  unsigned u = __float_as_uint(f);
  return (unsigned short)((u + 0x7FFF + ((u >> 16) & 1)) >> 16);
}

// ---------------- CSR build ----------------

__global__ void hist_kernel(const int* __restrict__ dst, int E, int ET, int* __restrict__ cnt){
  int e = blockIdx.x * blockDim.x + threadIdx.x;
  if (e >= ET) return;
  int d = (e < E) ? dst[e] : (e - E);   // self-loop edges appended
  atomicAdd(&cnt[d], 1);
}

__global__ void blocksum_kernel(const int* __restrict__ cnt, int N, int* __restrict__ bsum){
  int tid = threadIdx.x;
  int i = blockIdx.x * 256 + tid;
  int v = (i < N) ? cnt[i] : 0;
  #pragma unroll
  for (int off = 32; off >= 1; off >>= 1) v += __shfl_xor(v, off);
  __shared__ int ws[4];
  if ((tid & 63) == 0) ws[tid >> 6] = v;
  __syncthreads();
  if (tid == 0) bsum[blockIdx.x] = ws[0] + ws[1] + ws[2] + ws[3];
}

__global__ void scanb_kernel(int* __restrict__ bsum, int nb){
  __shared__ int buf[256];
  int tid = threadIdx.x;
  int v = (tid < nb) ? bsum[tid] : 0;
  buf[tid] = v;
  __syncthreads();
  #pragma unroll
  for (int off = 1; off < 256; off <<= 1){
    int t = (tid >= off) ? buf[tid - off] : 0;
    __syncthreads();
    buf[tid] += t;
    __syncthreads();
  }
  if (tid < nb) bsum[tid] = buf[tid] - v;  // exclusive
}

__global__ void scanfinal_kernel(const int* __restrict__ cnt, const int* __restrict__ bsum,
                                 int* __restrict__ ptr, int* __restrict__ cur, int N){
  __shared__ int buf[256];
  int tid = threadIdx.x;
  int i = blockIdx.x * 256 + tid;
  int v = (i < N) ? cnt[i] : 0;
  buf[tid] = v;
  __syncthreads();
  #pragma unroll
  for (int off = 1; off < 256; off <<= 1){
    int t = (tid >= off) ? buf[tid - off] : 0;
    __syncthreads();
    buf[tid] += t;
    __syncthreads();
  }
  int exc = buf[tid] - v + bsum[blockIdx.x];
  if (i < N){
    ptr[i] = exc; cur[i] = exc;
    if (i == N - 1) ptr[N] = exc + v;
  }
}

__global__ void scatter_kernel(const int* __restrict__ src, const int* __restrict__ dst,
                               int E, int ET, int* __restrict__ cur,
                               int* __restrict__ csr_src, int* __restrict__ csr_dst){
  int e = blockIdx.x * blockDim.x + threadIdx.x;
  if (e >= ET) return;
  int s, d;
  if (e < E){ s = src[e]; d = dst[e]; } else { s = e - E; d = e - E; }
  int pos = atomicAdd(&cur[d], 1);
  csr_src[pos] = s;
  csr_dst[pos] = d;
}

// ---------------- edge weights: w[i][h] = exp(leaky(a_src[s][h] + a_dst[d][h])) ----------------

__global__ void ew_kernel(const int* __restrict__ csr_src, const int* __restrict__ csr_dst,
                          const float* __restrict__ a_src, const float* __restrict__ a_dst,
                          float* __restrict__ w, int ET){
  int i = blockIdx.x * 256 + threadIdx.x;
  if (i >= ET) return;
  int s = csr_src[i], d = csr_dst[i];
  float4 as = *(const float4*)&a_src[(size_t)s * 4];
  float4 ad = *(const float4*)&a_dst[(size_t)d * 4];
  float4 r;
  float e;
  e = as.x + ad.x; e = e > 0.f ? e : 0.2f * e; r.x = __expf(e);
  e = as.y + ad.y; e = e > 0.f ? e : 0.2f * e; r.y = __expf(e);
  e = as.z + ad.z; e = e > 0.f ? e : 0.2f * e; r.z = __expf(e);
  e = as.w + ad.w; e = e > 0.f ? e : 0.2f * e; r.w = __expf(e);
  *(float4*)&w[(size_t)i * 4] = r;
}

// ---------------- W pre-split (all 3 layers in one launch) ----------------
// fp32 [K][256] -> bf16 hi/lo transposed [256][K]

__global__ void wsplit_kernel(const float* __restrict__ W0, unsigned short* __restrict__ h0,
                              unsigned short* __restrict__ l0,
                              const float* __restrict__ W1, unsigned short* __restrict__ h1,
                              unsigned short* __restrict__ l1,
                              const float* __restrict__ W2, unsigned short* __restrict__ h2,
                              unsigned short* __restrict__ l2){
  int idx = blockIdx.x * 256 + threadIdx.x;
  const float* W; unsigned short *hi, *lo; int K;
  if (idx < 128 * HC){ W = W0; hi = h0; lo = l0; K = 128; }
  else if (idx < (128 + 256) * HC){ idx -= 128 * HC; W = W1; hi = h1; lo = l1; K = 256; }
  else { idx -= (128 + 256) * HC; W = W2; hi = h2; lo = l2; K = 256; }
  int k = idx >> 8, n = idx & 255;
  float w = W[idx];
  unsigned short hb = f2bf(w);
  float hf = __uint_as_float((unsigned)hb << 16);
  unsigned short lb = f2bf(w - hf);
  hi[(size_t)n * K + k] = hb;
  lo[(size_t)n * K + k] = lb;
}

// ---------------- x pre-split: fp32 [N][128] -> hi/lo bf16 row-major ----------------

__global__ void xsplit_kernel(const float* __restrict__ x, int total4,
                              unsigned short* __restrict__ xhi, unsigned short* __restrict__ xlo){
  int i4 = blockIdx.x * 256 + threadIdx.x;
  if (i4 >= total4) return;
  float4 v = *(const float4*)&x[(size_t)i4 * 4];
  float va[4] = {v.x, v.y, v.z, v.w};
  unsigned short h4[4], l4[4];
  #pragma unroll
  for (int j = 0; j < 4; j++){
    unsigned short hb = f2bf(va[j]);
    float hf = __uint_as_float((unsigned)hb << 16);
    h4[j] = hb;
    l4[j] = f2bf(va[j] - hf);
  }
  *(ushort4*)&xhi[(size_t)i4 * 4] = make_ushort4(h4[0], h4[1], h4[2], h4[3]);
  *(ushort4*)&xlo[(size_t)i4 * 4] = make_ushort4(l4[0], l4[1], l4[2], l4[3]);
}

// ---------------- head-weight pre-split ----------------
// lw0 [64][128] -> bf16 hi/lo transposed [128][64]; lw1 [128][10] -> fp16 T padded [16][128]

__global__ void lwsplit_kernel(const float* __restrict__ lw0,
                               unsigned short* __restrict__ l0hi, unsigned short* __restrict__ l0lo,
                               const float* __restrict__ lw1, _Float16* __restrict__ l1T){
  int idx = blockIdx.x * 256 + threadIdx.x;
  if (idx < 8192){
    int n = idx & 127, k = idx >> 7;     // consecutive lanes -> consecutive n (coalesced read)
    float w = lw0[k * 128 + n];
    unsigned short hb = f2bf(w);
    float hf = __uint_as_float((unsigned)hb << 16);
    unsigned short lb = f2bf(w - hf);
    l0hi[n * 64 + k] = hb;
    l0lo[n * 64 + k] = lb;
  } else if (idx < 8192 + 2048){
    int id = idx - 8192;
    int n = id & 15, k = id >> 4;
    float w = (n < 10) ? lw1[k * 10 + n] : 0.f;
    l1T[n * 128 + k] = (_Float16)w;
  }
}

// ---------------- MFMA GEMM (3x bf16 split), pre-split A, fp16 C + fused att-score epilogue ----
// C[Mp,256] = A[Mp,K] @ B[K,256].  Mp % 128 == 0 (padded) -> NO bounds checks anywhere.
// A given as hi/lo bf16 [Mp][K]; B as hi/lo bf16 T [256][K].  128x128 tile, 4 waves, each 64x64.
// mfma_f32_16x16x32_bf16: A-frag lane: A[m=lane&15][k=(lane>>4)*8+j];
// B-frag lane: B[k=(lane>>4)*8+j][n=lane&15]; C/D: reg r -> row=(lane>>4)*4+r, col=lane&15.

__launch_bounds__(256, 2)
__global__ void gemm_mfma_kernel(const unsigned short* __restrict__ Ahi,
                                 const unsigned short* __restrict__ Alo,
                                 const unsigned short* __restrict__ BhiT,
                                 const unsigned short* __restrict__ BloT,
                                 _Float16* __restrict__ Cm,
                                 const float* __restrict__ att_s, const float* __restrict__ att_d,
                                 float* __restrict__ a_src, float* __restrict__ a_dst,
                                 int K){
  __shared__ unsigned short As_hi[128][40];   // stride 40 bf16 = 80B: 16B-aligned, 2-way banks
  __shared__ unsigned short As_lo[128][40];
  __shared__ unsigned short Bs_hi[128][40];   // BT layout: [n][k]
  __shared__ unsigned short Bs_lo[128][40];

  int tid = threadIdx.x;
  int m0 = blockIdx.x * 128, n0 = blockIdx.y * 128;
  int wave = tid >> 6, lane = tid & 63;
  int wm = (wave >> 1) * 64, wn = (wave & 1) * 64;
  int col = lane & 15, quad = lane >> 4;

  f32x4 acc[4][4];
  #pragma unroll
  for (int a = 0; a < 4; a++)
    #pragma unroll
    for (int b = 0; b < 4; b++)
      acc[a][b] = (f32x4){0.f, 0.f, 0.f, 0.f};

  for (int k0 = 0; k0 < K; k0 += 32){
    #pragma unroll
    for (int r = 0; r < 2; r++){
      int id = r * 256 + tid;
      int m = id >> 2, q = id & 3;
      size_t g = (size_t)(m0 + m) * K + k0 + q * 8;
      *(short8*)&As_hi[m][q * 8] = *(const short8*)&Ahi[g];
      *(short8*)&As_lo[m][q * 8] = *(const short8*)&Alo[g];
    }
    #pragma unroll
    for (int r = 0; r < 2; r++){
      int id = r * 256 + tid;
      int n = id >> 2, q = id & 3;
      size_t g = (size_t)(n0 + n) * K + k0 + q * 8;
      *(short8*)&Bs_hi[n][q * 8] = *(const short8*)&BhiT[g];
      *(short8*)&Bs_lo[n][q * 8] = *(const short8*)&BloT[g];
    }
    __syncthreads();

    short8 af[4][2], bf[4][2];
    #pragma unroll
    for (int t = 0; t < 4; t++){
      af[t][0] = *(const short8*)&As_hi[wm + t * 16 + col][quad * 8];
      af[t][1] = *(const short8*)&As_lo[wm + t * 16 + col][quad * 8];
      bf[t][0] = *(const short8*)&Bs_hi[wn + t * 16 + col][quad * 8];
      bf[t][1] = *(const short8*)&Bs_lo[wn + t * 16 + col][quad * 8];
    }
    #pragma unroll
    for (int mt = 0; mt < 4; mt++)
      #pragma unroll
      for (int nt = 0; nt < 4; nt++){
        acc[mt][nt] = __builtin_amdgcn_mfma_f32_16x16x32_bf16(af[mt][0], bf[nt][0], acc[mt][nt], 0, 0, 0);
        acc[mt][nt] = __builtin_amdgcn_mfma_f32_16x16x32_bf16(af[mt][1], bf[nt][0], acc[mt][nt], 0, 0, 0);
        acc[mt][nt] = __builtin_amdgcn_mfma_f32_16x16x32_bf16(af[mt][0], bf[nt][1], acc[mt][nt], 0, 0, 0);
      }
    __syncthreads();
  }

  // store C as fp16 (no bounds checks: Mp padded)
  #pragma unroll
  for (int mt = 0; mt < 4; mt++)
    #pragma unroll
    for (int nt = 0; nt < 4; nt++){
      int colg = n0 + wn + nt * 16 + col;
      #pragma unroll
      for (int r = 0; r < 4; r++){
        int row = m0 + wm + mt * 16 + quad * 4 + r;
        Cm[(size_t)row * HC + colg] = (_Float16)acc[mt][nt][r];
      }
    }

  // fused attention scores; this wave's 64 n-columns == one head
  int head = (n0 + wn) >> 6;
  float asv[4], adv[4];
  #pragma unroll
  for (int nt = 0; nt < 4; nt++){
    asv[nt] = att_s[head * CH + nt * 16 + col];
    adv[nt] = att_d[head * CH + nt * 16 + col];
  }
  #pragma unroll
  for (int mt = 0; mt < 4; mt++){
    float sp[4] = {0.f,0.f,0.f,0.f}, dp[4] = {0.f,0.f,0.f,0.f};
    #pragma unroll
    for (int nt = 0; nt < 4; nt++)
      #pragma unroll
      for (int r = 0; r < 4; r++){
        sp[r] += acc[mt][nt][r] * asv[nt];
        dp[r] += acc[mt][nt][r] * adv[nt];
      }
    #pragma unroll
    for (int off = 1; off <= 8; off <<= 1)
      #pragma unroll
      for (int r = 0; r < 4; r++){
        sp[r] += __shfl_xor(sp[r], off);
        dp[r] += __shfl_xor(dp[r], off);
      }
    if (col == 0){
      #pragma unroll
      for (int r = 0; r < 4; r++){
        int row = m0 + wm + mt * 16 + quad * 4 + r;
        a_src[row * HEADS + head] = sp[r];
        a_dst[row * HEADS + head] = dp[r];
      }
    }
  }
}

// ---------------- softmax aggregation: precomputed edge weights, fp16 gather ----------------
// block = node; wave = head; lane = eg(3b) x c8(3b), 2 streams (16 edges in flight).

__global__ void agg_kernel(const _Float16* __restrict__ h, const float* __restrict__ w,
                           const int* __restrict__ ptr, const int* __restrict__ csr_src,
                           const float* __restrict__ bias,
                           unsigned short* __restrict__ out_hi, unsigned short* __restrict__ out_lo,
                           int N, int mean_mode, const float* __restrict__ b2,
                           float* __restrict__ f2){
  __shared__ float sm[HEADS][CH];
  int n = blockIdx.x;
  int head = threadIdx.x >> 6;
  int lane = threadIdx.x & 63;
  int eg = lane >> 3, c8 = lane & 7;
  int beg = ptr[n], end = ptr[n + 1];

  float acc0[8] = {0.f,0.f,0.f,0.f,0.f,0.f,0.f,0.f};
  float acc1[8] = {0.f,0.f,0.f,0.f,0.f,0.f,0.f,0.f};
  float ss0 = 0.f, ss1 = 0.f;
  int i = beg + eg;
  for (; i + 8 < end; i += 16){
    int s0 = csr_src[i], s1 = csr_src[i + 8];
    float w0 = w[(size_t)i * 4 + head];
    float w1 = w[(size_t)(i + 8) * 4 + head];
    half8 h0 = *(const half8*)&h[(size_t)s0 * HC + head * CH + c8 * 8];
    half8 h1 = *(const half8*)&h[(size_t)s1 * HC + head * CH + c8 * 8];
    #pragma unroll
    for (int j = 0; j < 8; j++){
      acc0[j] += w0 * (float)h0[j];
      acc1[j] += w1 * (float)h1[j];
    }
    ss0 += w0; ss1 += w1;
  }
  if (i < end){
    int s0 = csr_src[i];
    float w0 = w[(size_t)i * 4 + head];
    half8 h0 = *(const half8*)&h[(size_t)s0 * HC + head * CH + c8 * 8];
    #pragma unroll
    for (int j = 0; j < 8; j++) acc0[j] += w0 * (float)h0[j];
    ss0 += w0;
  }
  float ss = ss0 + ss1;
  float acc[8];
  #pragma unroll
  for (int j = 0; j < 8; j++) acc[j] = acc0[j] + acc1[j];
  #pragma unroll
  for (int off = 8; off <= 32; off <<= 1){
    #pragma unroll
    for (int j = 0; j < 8; j++) acc[j] += __shfl_xor(acc[j], off);
    ss += __shfl_xor(ss, off);
  }
  float inv = 1.f / (ss + 1e-16f);
  #pragma unroll
  for (int j = 0; j < 8; j++) acc[j] *= inv;

  if (!mean_mode){
    if (eg == 0){
      const float* bp = &bias[head * CH + c8 * 8];
      short8 hi8, lo8;
      #pragma unroll
      for (int j = 0; j < 8; j++){
        float v = acc[j] + bp[j];
        unsigned short hb = f2bf(v);
        float hf = __uint_as_float((unsigned)hb << 16);
        hi8[j] = (short)hb;
        lo8[j] = (short)f2bf(v - hf);
      }
      size_t o = (size_t)n * HC + head * CH + c8 * 8;
      *(short8*)&out_hi[o] = hi8;
      *(short8*)&out_lo[o] = lo8;
    }
  } else {
    if (eg == 0){
      #pragma unroll
      for (int j = 0; j < 8; j++) sm[head][c8 * 8 + j] = acc[j];
    }
    __syncthreads();
    int t = threadIdx.x;
    if (t < CH)
      f2[(size_t)n * CH + t] =
        0.25f * (sm[0][t] + sm[1][t] + sm[2][t] + sm[3][t]) + b2[t];
  }
}

// ---------------- fused MFMA MLP head ----------------
// Per 64-row block: Z = relu(f2[64,64] @ lw0[64,128] + lb0)  (3x bf16 split, fp32-accurate)
// then out[64,10] = Z @ lw1[128,10] + lb1  (fp16 mfma).

__launch_bounds__(256, 2)
__global__ void head_mfma_kernel(const float* __restrict__ f2,
                                 const unsigned short* __restrict__ lw0hiT,
                                 const unsigned short* __restrict__ lw0loT,
                                 const _Float16* __restrict__ lw1T,
                                 const float* __restrict__ lb0,
                                 const float* __restrict__ lb1,
                                 float* __restrict__ outp, int N){
  __shared__ __align__(16) unsigned short L[27648];
  __shared__ __align__(16) _Float16 Ls[16][136];
  const int tid = threadIdx.x;
  const int wave = tid >> 6, lane = tid & 63;
  const int col = lane & 15, quad = lane >> 4;
  const int m0 = blockIdx.x * 64;

  { int n = tid >> 4, k = (tid & 15) * 8;
    *(half8*)&Ls[n][k] = *(const half8*)&lw1T[n * 128 + k]; }

  #pragma unroll
  for (int r = 0; r < 2; r++){
    int id = r * 256 + tid;
    int m = id >> 3, q = id & 7;
    int gm = m0 + m;
    float va[8];
    if (gm < N){
      float4 v0 = *(const float4*)&f2[(size_t)gm * CH + q * 8];
      float4 v1 = *(const float4*)&f2[(size_t)gm * CH + q * 8 + 4];
      va[0]=v0.x; va[1]=v0.y; va[2]=v0.z; va[3]=v0.w;
      va[4]=v1.x; va[5]=v1.y; va[6]=v1.z; va[7]=v1.w;
    } else {
      #pragma unroll
      for (int j = 0; j < 8; j++) va[j] = 0.f;
    }
    short8 hi8, lo8;
    #pragma unroll
    for (int j = 0; j < 8; j++){
      unsigned short hb = f2bf(va[j]);
      float hf = __uint_as_float((unsigned)hb << 16);
      hi8[j] = (short)hb;
      lo8[j] = (short)f2bf(va[j] - hf);
    }
    *(short8*)&L[m * 72 + q * 8] = hi8;
    *(short8*)&L[4608 + m * 72 + q * 8] = lo8;
  }
  #pragma unroll
  for (int r = 0; r < 4; r++){
    int id = r * 256 + tid;
    int n = id >> 3, q = id & 7;
    *(short8*)&L[9216 + n * 72 + q * 8]  = *(const short8*)&lw0hiT[n * 64 + q * 8];
    *(short8*)&L[18432 + n * 72 + q * 8] = *(const short8*)&lw0loT[n * 64 + q * 8];
  }
  __syncthreads();

  const int wn = wave * 32;
  f32x4 acc[4][2];
  #pragma unroll
  for (int a = 0; a < 4; a++)
    #pragma unroll
    for (int b = 0; b < 2; b++) acc[a][b] = (f32x4){0.f,0.f,0.f,0.f};

  #pragma unroll
  for (int ks = 0; ks < 2; ks++){
    int k = ks * 32 + quad * 8;
    short8 ah[4], al[4], bh[2], bl[2];
    #pragma unroll
    for (int mt = 0; mt < 4; mt++){
      ah[mt] = *(short8*)&L[(mt * 16 + col) * 72 + k];
      al[mt] = *(short8*)&L[4608 + (mt * 16 + col) * 72 + k];
    }
    #pragma unroll
    for (int nt = 0; nt < 2; nt++){
      bh[nt] = *(short8*)&L[9216 + (wn + nt * 16 + col) * 72 + k];
      bl[nt] = *(short8*)&L[18432 + (wn + nt * 16 + col) * 72 + k];
    }
    #pragma unroll
    for (int mt = 0; mt < 4; mt++)
      #pragma unroll
      for (int nt = 0; nt < 2; nt++){
        acc[mt][nt] = __builtin_amdgcn_mfma_f32_16x16x32_bf16(ah[mt], bh[nt], acc[mt][nt], 0, 0, 0);
        acc[mt][nt] = __builtin_amdgcn_mfma_f32_16x16x32_bf16(al[mt], bh[nt], acc[mt][nt], 0, 0, 0);
        acc[mt][nt] = __builtin_amdgcn_mfma_f32_16x16x32_bf16(ah[mt], bl[nt], acc[mt][nt], 0, 0, 0);
      }
  }
  __syncthreads();

  _Float16* Zp = (_Float16*)L;
  #pragma unroll
  for (int nt = 0; nt < 2; nt++){
    int n = wn + nt * 16 + col;
    float b = lb0[n];
    #pragma unroll
    for (int mt = 0; mt < 4; mt++)
      #pragma unroll
      for (int r2 = 0; r2 < 4; r2++){
        int m = mt * 16 + quad * 4 + r2;
        float z = acc[mt][nt][r2] + b;
        Zp[m * 136 + n] = (_Float16)fmaxf(z, 0.f);
      }
  }
  __syncthreads();

  f32x4 acc2 = (f32x4){0.f,0.f,0.f,0.f};
  #pragma unroll
  for (int ks = 0; ks < 4; ks++){
    int k = ks * 32 + quad * 8;
    half8 a2 = *(half8*)&Zp[(wave * 16 + col) * 136 + k];
    half8 b2v = *(half8*)&Ls[col][k];
    acc2 = __builtin_amdgcn_mfma_f32_16x16x32_f16(a2, b2v, acc2, 0, 0, 0);
  }
  if (col < 10){
    float bb = lb1[col];
    #pragma unroll
    for (int r2 = 0; r2 < 4; r2++){
      int row = m0 + wave * 16 + quad * 4 + r2;
      if (row < N) outp[(size_t)row * 10 + col] = acc2[r2] + bb;
    }
  }
}

// ---------------- launcher ----------------

extern "C" void kernel_launch(void* const* d_in, const int* in_sizes, int n_in,
                              void* d_out, int out_size, void* d_ws, size_t ws_size,
                              hipStream_t stream) {
  const float* x   = (const float*)d_in[0];
  const int*   ei  = (const int*)d_in[1];
  const float* W0  = (const float*)d_in[2];
  const float* as0 = (const float*)d_in[3];
  const float* ad0 = (const float*)d_in[4];
  const float* b0  = (const float*)d_in[5];
  const float* W1  = (const float*)d_in[6];
  const float* as1 = (const float*)d_in[7];
  const float* ad1 = (const float*)d_in[8];
  const float* b1  = (const float*)d_in[9];
  const float* W2  = (const float*)d_in[10];
  const float* as2 = (const float*)d_in[11];
  const float* ad2 = (const float*)d_in[12];
  const float* b2  = (const float*)d_in[13];
  const float* lw0 = (const float*)d_in[14];
  const float* lb0 = (const float*)d_in[15];
  const float* lw1 = (const float*)d_in[16];
  const float* lb1 = (const float*)d_in[17];
  float* outp = (float*)d_out;

  int N  = in_sizes[0] / 128;
  int E  = in_sizes[1] / 2;
  int ET = E + N;
  int nb = (N + 255) / 256;
  int Mp = ((N + 127) / 128) * 128;   // padded row count: GEMMs run bound-check-free

  char* ws = (char*)d_ws;
  _Float16* Hb = (_Float16*)ws;       ws += (size_t)Mp * HC * sizeof(_Float16);
  unsigned short* Fhi = (unsigned short*)ws; ws += (size_t)Mp * HC * 2;  // also holds xhi (Mp x 128)
  unsigned short* Flo = (unsigned short*)ws; ws += (size_t)Mp * HC * 2;  // also holds xlo
  float* f2  = (float*)ws; ws += (size_t)N * CH * sizeof(float);
  float* a_s = (float*)ws; ws += (size_t)Mp * HEADS * sizeof(float);
  float* a_d = (float*)ws; ws += (size_t)Mp * HEADS * sizeof(float);
  float* ewt = (float*)ws; ws += (size_t)ET * HEADS * sizeof(float);
  int* cnt   = (int*)ws;   ws += (size_t)N * sizeof(int);
  int* cur   = (int*)ws;   ws += (size_t)N * sizeof(int);
  int* ptrA  = (int*)ws;   ws += (size_t)(N + 1) * sizeof(int);
  int* bsum  = (int*)ws;   ws += (size_t)nb * sizeof(int);
  int* csr   = (int*)ws;   ws += (size_t)ET * sizeof(int);
  int* csrd  = (int*)ws;   ws += (size_t)ET * sizeof(int);
  unsigned short* w0hi = (unsigned short*)ws; ws += (size_t)128 * HC * 2;
  unsigned short* w0lo = (unsigned short*)ws; ws += (size_t)128 * HC * 2;
  unsigned short* w1hi = (unsigned short*)ws; ws += (size_t)HC * HC * 2;
  unsigned short* w1lo = (unsigned short*)ws; ws += (size_t)HC * HC * 2;
  unsigned short* w2hi = (unsigned short*)ws; ws += (size_t)HC * HC * 2;
  unsigned short* w2lo = (unsigned short*)ws; ws += (size_t)HC * HC * 2;
  unsigned short* l0hi = (unsigned short*)ws; ws += (size_t)8192 * 2;
  unsigned short* l0lo = (unsigned short*)ws; ws += (size_t)8192 * 2;
  _Float16* l1T        = (_Float16*)ws;       ws += (size_t)2048 * 2;

  const int* srcArr = ei;
  const int* dstArr = ei + E;

  // CSR build
  hipMemsetAsync(cnt, 0, (size_t)N * sizeof(int), stream);
  hist_kernel<<<(ET + 255) / 256, 256, 0, stream>>>(dstArr, E, ET, cnt);
  blocksum_kernel<<<nb, 256, 0, stream>>>(cnt, N, bsum);
  scanb_kernel<<<1, 256, 0, stream>>>(bsum, nb);
  scanfinal_kernel<<<nb, 256, 0, stream>>>(cnt, bsum, ptrA, cur, N);
  scatter_kernel<<<(ET + 255) / 256, 256, 0, stream>>>(srcArr, dstArr, E, ET, cur, csr, csrd);

  // weight pre-splits + x pre-split (x split lives in Fhi/Flo until agg layer-0 overwrites)
  wsplit_kernel<<<((128 + 256 + 256) * HC) / 256, 256, 0, stream>>>(
      W0, w0hi, w0lo, W1, w1hi, w1lo, W2, w2hi, w2lo);
  lwsplit_kernel<<<(8192 + 2048 + 255) / 256, 256, 0, stream>>>(lw0, l0hi, l0lo, lw1, l1T);
  xsplit_kernel<<<(N * 128 / 4 + 255) / 256, 256, 0, stream>>>(x, N * 128 / 4, Fhi, Flo);

  dim3 ggrid(Mp / 128, 2);
  int eb = (ET + 255) / 256;

  // layer 0: 128 -> 4x64, concat  (A = pre-split x in Fhi/Flo)
  gemm_mfma_kernel<<<ggrid, 256, 0, stream>>>(Fhi, Flo, w0hi, w0lo, Hb, as0, ad0, a_s, a_d, 128);
  ew_kernel<<<eb, 256, 0, stream>>>(csr, csrd, a_s, a_d, ewt, ET);
  agg_kernel<<<N, 256, 0, stream>>>(Hb, ewt, ptrA, csr, b0, Fhi, Flo, N, 0, nullptr, nullptr);

  // layer 1: 256 -> 4x64, concat
  gemm_mfma_kernel<<<ggrid, 256, 0, stream>>>(Fhi, Flo, w1hi, w1lo, Hb, as1, ad1, a_s, a_d, HC);
  ew_kernel<<<eb, 256, 0, stream>>>(csr, csrd, a_s, a_d, ewt, ET);
  agg_kernel<<<N, 256, 0, stream>>>(Hb, ewt, ptrA, csr, b1, Fhi, Flo, N, 0, nullptr, nullptr);

  // layer 2: 256 -> 4x64, mean over heads (+b2) -> f2 fp32
  gemm_mfma_kernel<<<ggrid, 256, 0, stream>>>(Fhi, Flo, w2hi, w2lo, Hb, as2, ad2, a_s, a_d, HC);
  ew_kernel<<<eb, 256, 0, stream>>>(csr, csrd, a_s, a_d, ewt, ET);
  agg_kernel<<<N, 256, 0, stream>>>(Hb, ewt, ptrA, csr, nullptr, nullptr, nullptr, N, 1, b2, f2);

  // MFMA MLP head
  head_mfma_kernel<<<(N + 63) / 64, 256, 0, stream>>>(f2, l0hi, l0lo, l1T, lb0, lb1, outp, N);
}